// Round 2
// baseline (455.677 us; speedup 1.0000x reference)
//
#include <hip/hip_runtime.h>
#include <hip/hip_bf16.h>
#include <cstdint>

typedef __bf16 bf16_t;
typedef __bf16 bf16x4 __attribute__((ext_vector_type(4)));
typedef __bf16 bf16x8 __attribute__((ext_vector_type(8)));
typedef float floatx4 __attribute__((ext_vector_type(4)));

#define LNEPS 1e-5f

__device__ inline void async_copy16(const bf16_t* g, bf16_t* l) {
    __builtin_amdgcn_global_load_lds((const __attribute__((address_space(1))) void*)g,
                                     (__attribute__((address_space(3))) void*)l,
                                     16, 0, 0);
}

// ---------------------------------------------------------------------------
// K0: transpose proj_w (768x512 fp32) -> Wt (512x768 bf16), K-contig B operand
// ---------------------------------------------------------------------------
__global__ __launch_bounds__(256)
void k_transpose_w(const float* __restrict__ w, bf16_t* __restrict__ wt) {
    __shared__ bf16_t tile[32][33];
    const int bx = blockIdx.x;            // n-tile (16)
    const int by = blockIdx.y;            // k-tile (24)
    const int tx = threadIdx.x & 31, ty = threadIdx.x >> 5;  // 32x8
    for (int i = ty; i < 32; i += 8)
        tile[i][tx] = (bf16_t)w[(by*32 + i)*512 + bx*32 + tx];
    __syncthreads();
    for (int i = ty; i < 32; i += 8)
        wt[(bx*32 + i)*768 + by*32 + tx] = tile[tx][i];
}

// ---------------------------------------------------------------------------
// K1: xp = x[:,1:,:] @ Wt^T + b, fused per-head LayerNorm AND column sums.
// Reads x fp32 directly (k_cvt_x eliminated): A is reg-staged
// (float4 x4 -> cvt -> ds_write_b128 x2), issue-early / write-late around the
// MFMA cluster (T14); B via global_load_lds. Double-buffered LDS, one barrier
// per K-step. Epilogue: LN (shuffle-only, wave owns full head) + per-column
// partial sums -> atomicAdd into csum (k_colsum eliminated).
// grid (4 heads fastest, 392 m-tiles): 4 blocks sharing an A panel are
// co-resident -> one HBM fetch of x per panel.
// ---------------------------------------------------------------------------
__global__ __launch_bounds__(256, 3)
void k_proj_ln(const float* __restrict__ x, const bf16_t* __restrict__ wt,
               const float* __restrict__ pb, const float* __restrict__ lng,
               const float* __restrict__ lnb, bf16_t* __restrict__ hn,
               float* __restrict__ csum)
{
    __shared__ bf16_t As[2][128*32];
    __shared__ bf16_t Bs[2][128*32];

    const int t = threadIdx.x;
    const int lane = t & 63;
    const int wv = t >> 6;                // wave 0..3 -> rows wv*32..wv*32+31
    const int q = lane >> 4;
    const int c = lane & 15;
    const int h  = blockIdx.x;            // head 0..3
    const int m0 = blockIdx.y * 128;

    // A staging: thread t covers hn-row (t>>1), 16 floats at col (t&1)*16
    const int arow = t >> 1;
    const int acol = (t & 1) * 16;
    const int agm  = m0 + arow;
    const int ab   = agm / 196;
    const int al   = agm - ab * 196;
    const float* ag = x + ((long)(ab * 197 + al + 1) * 768) + acol;

    // B staging via global_load_lds: rows srow, srow+64 of head panel
    const int srow  = t >> 2;
    const int skoff = (t & 3) * 8;
    const bf16_t* bg = wt + (h*128 + srow) * 768 + skoff;

    floatx4 acc[2][8];
#pragma unroll
    for (int i = 0; i < 2; i++)
#pragma unroll
        for (int j = 0; j < 8; j++)
#pragma unroll
            for (int r = 0; r < 4; r++) acc[i][j][r] = 0.f;

    // prologue: stage k=0 into buf 0
    floatx4 a0 = *(const floatx4*)(ag);
    floatx4 a1 = *(const floatx4*)(ag + 4);
    floatx4 a2 = *(const floatx4*)(ag + 8);
    floatx4 a3 = *(const floatx4*)(ag + 12);
    async_copy16(bg,          &Bs[0][t*8]);
    async_copy16(bg + 64*768, &Bs[0][2048 + t*8]);
    {
        bf16x8 w0, w1;
#pragma unroll
        for (int e = 0; e < 4; e++) {
            w0[e] = (bf16_t)a0[e]; w0[e+4] = (bf16_t)a1[e];
            w1[e] = (bf16_t)a2[e]; w1[e+4] = (bf16_t)a3[e];
        }
        *(bf16x8*)&As[0][arow*32 + acol]     = w0;
        *(bf16x8*)&As[0][arow*32 + acol + 8] = w1;
    }
    __syncthreads();

    int buf = 0;
    for (int ks = 0; ks < 24; ks++) {
        const int nbuf = buf ^ 1;
        if (ks < 23) {
            const int kn = (ks + 1) * 32;
            a0 = *(const floatx4*)(ag + kn);
            a1 = *(const floatx4*)(ag + kn + 4);
            a2 = *(const floatx4*)(ag + kn + 8);
            a3 = *(const floatx4*)(ag + kn + 12);
            async_copy16(bg + kn,          &Bs[nbuf][t*8]);
            async_copy16(bg + 64*768 + kn, &Bs[nbuf][2048 + t*8]);
        }
        bf16x8 af[2], bfr[8];
#pragma unroll
        for (int i = 0; i < 2; i++)
            af[i] = *(const bf16x8*)&As[buf][(wv*32 + i*16 + c)*32 + q*8];
#pragma unroll
        for (int j = 0; j < 8; j++)
            bfr[j] = *(const bf16x8*)&Bs[buf][(j*16 + c)*32 + q*8];
#pragma unroll
        for (int i = 0; i < 2; i++)
#pragma unroll
            for (int j = 0; j < 8; j++)
                acc[i][j] = __builtin_amdgcn_mfma_f32_16x16x32_bf16(af[i], bfr[j], acc[i][j], 0, 0, 0);
        if (ks < 23) {
            bf16x8 w0, w1;
#pragma unroll
            for (int e = 0; e < 4; e++) {
                w0[e] = (bf16_t)a0[e]; w0[e+4] = (bf16_t)a1[e];
                w1[e] = (bf16_t)a2[e]; w1[e+4] = (bf16_t)a3[e];
            }
            *(bf16x8*)&As[nbuf][arow*32 + acol]     = w0;
            *(bf16x8*)&As[nbuf][arow*32 + acol + 8] = w1;
        }
        __syncthreads();          // drains B gloads + A ds_writes for nbuf
        buf = nbuf;
    }

    // epilogue: +bias, LayerNorm over this wave's head (128 cols = 8j x 16c),
    // plus per-column partial sums split at the (at most one) batch boundary
    float bias[8], gg[8], bb[8];
#pragma unroll
    for (int j = 0; j < 8; j++) {
        const int d = j*16 + c;
        bias[j] = pb[h*128 + d];
        gg[j]   = lng[d];
        bb[j]   = lnb[d];
    }
    float cs0[8], cs1[8];
#pragma unroll
    for (int j = 0; j < 8; j++) { cs0[j] = 0.f; cs1[j] = 0.f; }
    const int b0 = m0 / 196;
    const int bL = (m0 + 127) / 196;
#pragma unroll
    for (int i = 0; i < 2; i++) {
#pragma unroll
        for (int r = 0; r < 4; r++) {
            float s = 0.f, s2 = 0.f;
#pragma unroll
            for (int j = 0; j < 8; j++) {
                const float v = acc[i][j][r] + bias[j];
                acc[i][j][r] = v;
                s += v; s2 += v*v;
            }
#pragma unroll
            for (int o = 1; o < 16; o <<= 1) { s += __shfl_xor(s, o); s2 += __shfl_xor(s2, o); }
            const float mu = s * (1.f/128.f);
            const float ms = s2 * (1.f/128.f);
            const float rstd = rsqrtf(ms - mu*mu + LNEPS);
            const int gm = m0 + wv*32 + i*16 + q*4 + r;
            const int bI = gm / 196, l = gm - bI*196;
            bf16_t* dst = hn + (((h*256 + bI)*196 + l) << 7);
            const bool first = (bI == b0);
#pragma unroll
            for (int j = 0; j < 8; j++) {
                const float v = (acc[i][j][r] - mu)*rstd*gg[j] + bb[j];
                dst[j*16 + c] = (bf16_t)v;
                cs0[j] += first ? v : 0.f;
                cs1[j] += first ? 0.f : v;
            }
        }
    }
    // reduce column sums: over q (shfl), over waves (LDS), atomicAdd
    float* scr = (float*)As;              // [wv][bucket][128] floats = 4 KB
#pragma unroll
    for (int j = 0; j < 8; j++) {
        float s0 = cs0[j], s1 = cs1[j];
        s0 += __shfl_xor(s0, 16); s0 += __shfl_xor(s0, 32);
        s1 += __shfl_xor(s1, 16); s1 += __shfl_xor(s1, 32);
        if (q == 0) {
            scr[(wv*2 + 0)*128 + j*16 + c] = s0;
            scr[(wv*2 + 1)*128 + j*16 + c] = s1;
        }
    }
    __syncthreads();
    {
        const int bucket = t >> 7, d = t & 127;
        if (bucket == 0 || bL > b0) {
            const float s = scr[(0*2 + bucket)*128 + d] + scr[(1*2 + bucket)*128 + d]
                          + scr[(2*2 + bucket)*128 + d] + scr[(3*2 + bucket)*128 + d];
            atomicAdd(&csum[((h*256 + b0 + bucket) << 7) + d], s);
        }
    }
}

// ---------------------------------------------------------------------------
// K2: per (p,b): raw = x1^T @ x2 (K=196 padded to 224), centering correction,
//     column L2 normalize over d, write cov[b][p][d][e] fp32
// ---------------------------------------------------------------------------
__global__ __launch_bounds__(256, 2)
void k_cov(const bf16_t* __restrict__ hn, const float* __restrict__ colsum,
           float* __restrict__ cov)
{
    __shared__ bf16_t x1s[128*40];
    __shared__ bf16_t x2s[128*40];
    __shared__ float rs1[128], rs2[128];
    __shared__ float colsq[2][128];
    __shared__ float nrm_inv[128];
    __shared__ float mu_s[2];

    const int t = threadIdx.x;
    const int lane = t & 63;
    const int wv = t >> 6;
    const int wr = wv >> 1, wc = wv & 1;
    const int q = lane >> 4;
    const int c = lane & 15;
    const int b = blockIdx.x;
    const int p = blockIdx.y;

    const bf16_t* X1 = hn + (((p*256 + b)*196) << 7);
    const bf16_t* X2 = hn + ((((p+1)*256 + b)*196) << 7);

    if (t < 128) rs1[t] = colsum[((p*256 + b) << 7) + t];
    else         rs2[t & 127] = colsum[(((p+1)*256 + b) << 7) + (t & 127)];
    __syncthreads();
    if (wv == 0) {
        float s = rs1[lane] + rs1[lane + 64];
#pragma unroll
        for (int o = 1; o < 64; o <<= 1) s += __shfl_xor(s, o);
        if (lane == 0) mu_s[0] = s * (1.f/(196.f*128.f));
    } else if (wv == 1) {
        float s = rs2[lane] + rs2[lane + 64];
#pragma unroll
        for (int o = 1; o < 64; o <<= 1) s += __shfl_xor(s, o);
        if (lane == 0) mu_s[1] = s * (1.f/(196.f*128.f));
    }

    floatx4 acc[4][4];
#pragma unroll
    for (int i = 0; i < 4; i++)
#pragma unroll
        for (int j = 0; j < 4; j++)
#pragma unroll
            for (int r = 0; r < 4; r++) acc[i][j][r] = 0.f;

    const int nl = t >> 3;
    const int d0 = (t & 7) * 16;

    for (int n0 = 0; n0 < 224; n0 += 32) {
        __syncthreads();
        const int n = n0 + nl;
        bf16x8 va, vb, wa, wb;
        if (n < 196) {
            const bf16_t* s1 = X1 + (n << 7) + d0;
            const bf16_t* s2 = X2 + (n << 7) + d0;
            va = *(const bf16x8*)s1;
            vb = *(const bf16x8*)(s1 + 8);
            wa = *(const bf16x8*)s2;
            wb = *(const bf16x8*)(s2 + 8);
        } else {
#pragma unroll
            for (int e = 0; e < 8; e++) {
                va[e] = (bf16_t)0.f; vb[e] = (bf16_t)0.f;
                wa[e] = (bf16_t)0.f; wb[e] = (bf16_t)0.f;
            }
        }
#pragma unroll
        for (int e = 0; e < 8; e++) {
            x1s[(d0 + e)*40 + nl]     = va[e];
            x1s[(d0 + 8 + e)*40 + nl] = vb[e];
            x2s[(d0 + e)*40 + nl]     = wa[e];
            x2s[(d0 + 8 + e)*40 + nl] = wb[e];
        }
        __syncthreads();
        bf16x8 af[4], bfr[4];
#pragma unroll
        for (int i = 0; i < 4; i++)
            af[i] = *(const bf16x8*)&x1s[(wr*64 + i*16 + c)*40 + q*8];
#pragma unroll
        for (int j = 0; j < 4; j++)
            bfr[j] = *(const bf16x8*)&x2s[(wc*64 + j*16 + c)*40 + q*8];
#pragma unroll
        for (int i = 0; i < 4; i++)
#pragma unroll
            for (int j = 0; j < 4; j++)
                acc[i][j] = __builtin_amdgcn_mfma_f32_16x16x32_bf16(af[i], bfr[j], acc[i][j], 0, 0, 0);
    }

    const float mu1 = mu_s[0], mu2 = mu_s[1];
    const float invL = 1.f/196.f;
    float csq[4] = {0.f, 0.f, 0.f, 0.f};
#pragma unroll
    for (int i = 0; i < 4; i++)
#pragma unroll
        for (int j = 0; j < 4; j++)
#pragma unroll
            for (int r = 0; r < 4; r++) {
                const int d = wr*64 + i*16 + q*4 + r;
                const int e = wc*64 + j*16 + c;
                const float v = acc[i][j][r]*invL - mu2*rs1[d]*invL - mu1*rs2[e]*invL + mu1*mu2;
                acc[i][j][r] = v;
                csq[j] += v*v;
            }
#pragma unroll
    for (int j = 0; j < 4; j++) {
        float s = csq[j];
        s += __shfl_xor(s, 16);
        s += __shfl_xor(s, 32);
        csq[j] = s;
    }
    if (q == 0) {
#pragma unroll
        for (int j = 0; j < 4; j++) colsq[wr][wc*64 + j*16 + c] = csq[j];
    }
    __syncthreads();
    if (t < 128) {
        const float nr = sqrtf(colsq[0][t] + colsq[1][t]);
        nrm_inv[t] = 1.f / fmaxf(nr, 1e-12f);
    }
    __syncthreads();
    float* dst = cov + ((long)b*3 + p)*16384;
#pragma unroll
    for (int i = 0; i < 4; i++)
#pragma unroll
        for (int j = 0; j < 4; j++) {
            const int e = wc*64 + j*16 + c;
            const float ni = nrm_inv[e];
#pragma unroll
            for (int r = 0; r < 4; r++) {
                const int d = wr*64 + i*16 + q*4 + r;
                dst[(d << 7) + e] = acc[i][j][r] * ni;
            }
        }
}

// ---------------------------------------------------------------------------
// K3: fused conv1+GELU+conv2; 2 blocks per batch (conv2 y-halves) -> 512
// blocks = 2 blocks/CU. Z slice (<=33 rows, 1-row overlap) kept in LDS.
// ---------------------------------------------------------------------------
__global__ __launch_bounds__(256)
void k_convs(const float* __restrict__ cov, const float* __restrict__ w1,
             const float* __restrict__ w2, bf16_t* __restrict__ Xb)
{
    __shared__ float Z[3*33*63];          // 24.9 KB
    __shared__ float W1s[81];
    __shared__ float W2s[81];
    const int t = threadIdx.x;
    const int b = blockIdx.x >> 1, half = blockIdx.x & 1;
    const int zy0 = half ? 32 : 0;        // first global Z row this block needs
    const int nzy = half ? 31 : 33;       // Z rows computed
    const int y20 = half ? 16 : 0;        // first conv2 output row
    const int ny2 = half ? 15 : 16;       // conv2 output rows
    if (t < 81) { W1s[t] = w1[t]; W2s[t] = w2[t]; }
    __syncthreads();
    const float* C = cov + (long)b*3*16384;
    const int ztot = 3*nzy*63;
    for (int idx = t; idx < ztot; idx += 256) {
        const int o = idx / (nzy*63), rem = idx - o*(nzy*63);
        const int yl = rem / 63, xx = rem - yl*63;
        const int y = zy0 + yl;
        float a = 0.f;
#pragma unroll
        for (int i = 0; i < 3; i++) {
            const float* Ci = C + i*16384 + (2*y)*128 + 2*xx;
            const float* Wi = &W1s[o*27 + i*9];
            a += Ci[0]*Wi[0]   + Ci[1]*Wi[1]   + Ci[2]*Wi[2]
               + Ci[128]*Wi[3] + Ci[129]*Wi[4] + Ci[130]*Wi[5]
               + Ci[256]*Wi[6] + Ci[257]*Wi[7] + Ci[258]*Wi[8];
        }
        Z[o*2079 + yl*63 + xx] = 0.5f*a*(1.0f + erff(a*0.70710678118654752f));
    }
    __syncthreads();
    const int c2tot = 3*ny2*31;
    for (int idx = t; idx < c2tot; idx += 256) {
        const int o = idx / (ny2*31), rem = idx - o*(ny2*31);
        const int y2l = rem / 31, x2 = rem - y2l*31;
        float a = 0.f;
#pragma unroll
        for (int i = 0; i < 3; i++) {
            const float* Zi = Z + i*2079 + (2*y2l)*63 + 2*x2;
            const float* Wi = &W2s[(o*3+i)*9];
            a += Zi[0]*Wi[0]   + Zi[1]*Wi[1]   + Zi[2]*Wi[2]
               + Zi[63]*Wi[3]  + Zi[64]*Wi[4]  + Zi[65]*Wi[5]
               + Zi[126]*Wi[6] + Zi[127]*Wi[7] + Zi[128]*Wi[8];
        }
        const int oy2 = y20 + y2l;
        Xb[(long)b*3712 + 768 + o*961 + oy2*31 + x2] = (bf16_t)a;
    }
}

// ---------------------------------------------------------------------------
// K4a: cls fp32 -> bf16 into Xb[b][0..767]; zero K-pad; zero csum slice
// ---------------------------------------------------------------------------
__global__ __launch_bounds__(256)
void k_cvt_cls(const float* __restrict__ cls, bf16_t* __restrict__ Xb,
               float* __restrict__ csum)
{
    const int t = threadIdx.x, b = blockIdx.x;
    for (int k = t; k < 768; k += 256)
        Xb[b*3712 + k] = (bf16_t)cls[b*768 + k];
    if (t < 61) Xb[b*3712 + 3651 + t] = (bf16_t)0.f;
    float* cz = csum + b*512;             // 256 blocks x 512 = 131072 floats
    cz[t] = 0.f; cz[t + 256] = 0.f;
}

// ---------------------------------------------------------------------------
// K4b: build Wb[n][k] bf16, n<1024 (1000 pad), k<3712 (3651 pad)
// ---------------------------------------------------------------------------
__global__ __launch_bounds__(256)
void k_cvt_w(const float* __restrict__ W1, const float* __restrict__ W2,
             bf16_t* __restrict__ Wb)
{
    __shared__ bf16_t tile[32][33];
    const int k0 = blockIdx.x * 32;       // 116 tiles
    const int n0 = blockIdx.y * 32;       // 32 tiles
    const int tx = threadIdx.x & 31, ty = threadIdx.x >> 5;
    for (int i = ty; i < 32; i += 8) {
        const int k = k0 + i, n = n0 + tx;
        float v = 0.f;
        if (n < 1000 && k < 3651)
            v = (k < 768) ? W1[k*1000 + n] : W2[(k-768)*1000 + n];
        tile[i][tx] = (bf16_t)v;
    }
    __syncthreads();
    for (int i = ty; i < 32; i += 8)
        Wb[(n0 + i)*3712 + k0 + tx] = tile[tx][i];
}

// ---------------------------------------------------------------------------
// K4c: MFMA GEMM partial[s][m][n] = Xb[m][ks..] @ Wb[n][ks..]^T
// grid (nt=8, mt=2, split=4); 128x128 tile, K-split 928 each
// ---------------------------------------------------------------------------
__global__ __launch_bounds__(256, 2)
void k_gemm_cls(const bf16_t* __restrict__ Xb, const bf16_t* __restrict__ Wb,
                float* __restrict__ partial)
{
    __shared__ bf16_t As[128*32];
    __shared__ bf16_t Bs[128*32];

    const int t = threadIdx.x;
    const int lane = t & 63;
    const int wv = t >> 6;
    const int wr = wv >> 1, wc = wv & 1;
    const int q = lane >> 4;
    const int c = lane & 15;
    const int nt = blockIdx.x;
    const int mt = blockIdx.y;
    const int sp = blockIdx.z;

    const int srow  = t >> 2;
    const int skoff = (t & 3) * 8;
    const int m0 = mt * 128, n0 = nt * 128;
    const int kbase = sp * 928;
    const bf16_t* ag0 = Xb + (m0 + srow) * 3712 + kbase + skoff;
    const bf16_t* ag1 = Xb + (m0 + srow + 64) * 3712 + kbase + skoff;
    const bf16_t* bg0 = Wb + (n0 + srow) * 3712 + kbase + skoff;
    const bf16_t* bg1 = Wb + (n0 + srow + 64) * 3712 + kbase + skoff;

    floatx4 acc[4][4];
#pragma unroll
    for (int i = 0; i < 4; i++)
#pragma unroll
        for (int j = 0; j < 4; j++)
#pragma unroll
            for (int r = 0; r < 4; r++) acc[i][j][r] = 0.f;

    for (int k0 = 0; k0 < 928; k0 += 32) {
        __syncthreads();
        async_copy16(ag0 + k0, &As[t*8]);
        async_copy16(ag1 + k0, &As[2048 + t*8]);
        async_copy16(bg0 + k0, &Bs[t*8]);
        async_copy16(bg1 + k0, &Bs[2048 + t*8]);
        __syncthreads();
        bf16x8 af[4], bfr[4];
#pragma unroll
        for (int i = 0; i < 4; i++)
            af[i] = *(const bf16x8*)&As[(wr*64 + i*16 + c)*32 + q*8];
#pragma unroll
        for (int j = 0; j < 4; j++)
            bfr[j] = *(const bf16x8*)&Bs[(wc*64 + j*16 + c)*32 + q*8];
#pragma unroll
        for (int i = 0; i < 4; i++)
#pragma unroll
            for (int j = 0; j < 4; j++)
                acc[i][j] = __builtin_amdgcn_mfma_f32_16x16x32_bf16(af[i], bfr[j], acc[i][j], 0, 0, 0);
    }

    float* base = partial + ((long)sp*256 + m0)*1024 + n0;
#pragma unroll
    for (int i = 0; i < 4; i++)
#pragma unroll
        for (int r = 0; r < 4; r++) {
            const int row = wr*64 + i*16 + q*4 + r;
#pragma unroll
            for (int j = 0; j < 4; j++)
                base[row*1024 + wc*64 + j*16 + c] = acc[i][j][r];
        }
}

// ---------------------------------------------------------------------------
// K4d: out[m][n] = 0.5*(sum_s partial[s][m][n] + b1[n] + b2[n]), n<1000
// ---------------------------------------------------------------------------
__global__ __launch_bounds__(256)
void k_cls_fin(const float* __restrict__ partial, const float* __restrict__ b1,
               const float* __restrict__ b2, float* __restrict__ out)
{
    const int idx = blockIdx.x * 256 + threadIdx.x;   // 256,000
    const int m = idx / 1000, n = idx - m*1000;
    float s = partial[(m)*1024 + n] + partial[(256 + m)*1024 + n]
            + partial[(512 + m)*1024 + n] + partial[(768 + m)*1024 + n];
    out[idx] = 0.5f*(s + b1[n] + b2[n]);
}

// ---------------------------------------------------------------------------
extern "C" void kernel_launch(void* const* d_in, const int* in_sizes, int n_in,
                              void* d_out, int out_size, void* d_ws, size_t ws_size,
                              hipStream_t stream) {
    const float* cls = (const float*)d_in[0];
    const float* x   = (const float*)d_in[1];
    const float* pw  = (const float*)d_in[2];
    const float* pb  = (const float*)d_in[3];
    const float* lng = (const float*)d_in[4];
    const float* lnb = (const float*)d_in[5];
    const float* c1w = (const float*)d_in[6];
    const float* c2w = (const float*)d_in[7];
    const float* w1  = (const float*)d_in[8];
    const float* b1  = (const float*)d_in[9];
    const float* w2  = (const float*)d_in[10];
    const float* b2  = (const float*)d_in[11];

    char* ws = (char*)d_ws;
    // lifetimes:
    //   hn      [0, 51,380,224)                 proj_ln out -> cov in
    //   covb    [51,380,224, +50,331,648)       cov out -> convs in
    //   wt      [128,450,560, +786,432)         dead after proj_ln
    //   csum    [129,236,992, +524,288)
    //   Xb      [129,761,280, +1,900,544)
    //   Wb      [131,661,824, +7,602,176)
    //   part    [139,264,000, +4,194,304)
    bf16_t* hn    = (bf16_t*)(ws);
    float*  covb  = (float*) (ws + 51380224ull);
    bf16_t* wt    = (bf16_t*)(ws + 128450560ull);
    float*  csum  = (float*) (ws + 129236992ull);
    bf16_t* Xb    = (bf16_t*)(ws + 129761280ull);
    bf16_t* Wb    = (bf16_t*)(ws + 131661824ull);
    float*  part  = (float*) (ws + 139264000ull);
    float*  out   = (float*)d_out;

    k_transpose_w<<<dim3(16, 24), 256, 0, stream>>>(pw, wt);
    k_cvt_cls<<<256, 256, 0, stream>>>(cls, Xb, csum);
    k_cvt_w<<<dim3(116, 32), 256, 0, stream>>>(w1, w2, Wb);
    k_proj_ln<<<dim3(4, 392), 256, 0, stream>>>(x, wt, pb, lng, lnb, hn, csum);
    k_cov<<<dim3(256, 3), 256, 0, stream>>>(hn, csum, covb);
    k_convs<<<512, 256, 0, stream>>>(covb, c1w, c2w, Xb);
    k_gemm_cls<<<dim3(8, 2, 4), 256, 0, stream>>>(Xb, Wb, part);
    k_cls_fin<<<1000, 256, 0, stream>>>(part, b1, b2, out);
}

// Round 3
// 447.244 us; speedup vs baseline: 1.0189x; 1.0189x over previous
//
#include <hip/hip_runtime.h>
#include <hip/hip_bf16.h>
#include <cstdint>

typedef __bf16 bf16_t;
typedef __bf16 bf16x4 __attribute__((ext_vector_type(4)));
typedef __bf16 bf16x8 __attribute__((ext_vector_type(8)));
typedef float floatx4 __attribute__((ext_vector_type(4)));

#define LNEPS 1e-5f

__device__ inline void async_copy16(const bf16_t* g, bf16_t* l) {
    __builtin_amdgcn_global_load_lds((const __attribute__((address_space(1))) void*)g,
                                     (__attribute__((address_space(3))) void*)l,
                                     16, 0, 0);
}

// ---------------------------------------------------------------------------
// K0: transpose proj_w (768x512 fp32) -> Wt (512x768 bf16), K-contig B operand
// ---------------------------------------------------------------------------
__global__ __launch_bounds__(256)
void k_transpose_w(const float* __restrict__ w, bf16_t* __restrict__ wt) {
    __shared__ bf16_t tile[32][33];
    const int bx = blockIdx.x;            // n-tile (16)
    const int by = blockIdx.y;            // k-tile (24)
    const int tx = threadIdx.x & 31, ty = threadIdx.x >> 5;  // 32x8
    for (int i = ty; i < 32; i += 8)
        tile[i][tx] = (bf16_t)w[(by*32 + i)*512 + bx*32 + tx];
    __syncthreads();
    for (int i = ty; i < 32; i += 8)
        wt[(bx*32 + i)*768 + by*32 + tx] = tile[tx][i];
}

// ---------------------------------------------------------------------------
// K1: xp = x[:,1:,:] @ Wt^T + b, fused per-head LN + column sums.
// ONE block per 64-row m-tile computes ALL 4 heads (N=512): x read exactly
// once from HBM (no cross-block A reuse needed). 512 threads = 8 waves
// (2 row-groups x 4 heads); each wave: 32 rows x 128 cols (one head) ->
// shuffle-only LN. A reg-staged fp32->bf16 (issue at phase top, cvt+ds_write
// at phase end, T14); B via global_load_lds. Double-buffered LDS with
// counted-vmcnt raw barriers (T3/T4): loads never drained to 0 in-loop.
// ---------------------------------------------------------------------------
__global__ __launch_bounds__(512, 4)
void k_proj_ln(const float* __restrict__ x, const bf16_t* __restrict__ wt,
               const float* __restrict__ pb, const float* __restrict__ lng,
               const float* __restrict__ lnb, bf16_t* __restrict__ hn,
               float* __restrict__ csum)
{
    __shared__ bf16_t As[2][64*32];       // 8 KB
    __shared__ bf16_t Bs[2][512*32];      // 64 KB

    const int t = threadIdx.x;
    const int lane = t & 63;
    const int wv = t >> 6;                // 0..7
    const int wr = wv >> 2;               // row group (32 rows)
    const int wc = wv & 3;                // head
    const int q = lane >> 4;
    const int c = lane & 15;
    const int m0 = blockIdx.x * 64;

    // A staging: thread t covers row (t>>3), 4 fp32 at col (t&7)*4
    const int arow = t >> 3;
    const int acb  = (t & 7) * 4;
    const int agm  = m0 + arow;
    const int ab   = agm / 196;
    const int al   = agm - ab * 196;
    const float* ag = x + ((long)(ab * 197 + al + 1) * 768) + acb;

#define BSTAGE(B, kk)                                                          \
    {                                                                          \
        _Pragma("unroll")                                                      \
        for (int m_ = 0; m_ < 4; m_++)                                         \
            async_copy16(wt + (m_*128 + (t >> 2))*768 + (kk)*32 + (t & 3)*8,   \
                         &Bs[B][m_*4096 + t*8]);                               \
    }

    floatx4 acc[2][8];
#pragma unroll
    for (int i = 0; i < 2; i++)
#pragma unroll
        for (int j = 0; j < 8; j++)
#pragma unroll
            for (int r = 0; r < 4; r++) acc[i][j][r] = 0.f;

    // prologue: tiles 0 and 1
    floatx4 a0 = *(const floatx4*)(ag);
    floatx4 a1 = *(const floatx4*)(ag + 32);
    BSTAGE(0, 0);
    BSTAGE(1, 1);
    {
        bf16x4 w4;
#pragma unroll
        for (int e = 0; e < 4; e++) w4[e] = (bf16_t)a0[e];
        *(bf16x4*)&As[0][arow*32 + acb] = w4;
#pragma unroll
        for (int e = 0; e < 4; e++) w4[e] = (bf16_t)a1[e];
        *(bf16x4*)&As[1][arow*32 + acb] = w4;
    }

    floatx4 a_next;
    for (int ks = 0; ks < 23; ks++) {
        const int buf = ks & 1;
        // vmcnt(4): tile ks's B gloads complete, tile ks+1's 4 stay in flight
        asm volatile("s_waitcnt vmcnt(4)" ::: "memory");
        asm volatile("s_waitcnt lgkmcnt(0)" ::: "memory");
        __builtin_amdgcn_s_barrier();
        // issue A load for tile ks+2 (consumed at phase end -> MFMA window)
        if (ks < 22) a_next = *(const floatx4*)(ag + (ks + 2) * 32);
        bf16x8 af[2], bfr[8];
#pragma unroll
        for (int i = 0; i < 2; i++)
            af[i] = *(const bf16x8*)&As[buf][(wr*32 + i*16 + c)*32 + q*8];
#pragma unroll
        for (int j = 0; j < 8; j++)
            bfr[j] = *(const bf16x8*)&Bs[buf][(wc*128 + j*16 + c)*32 + q*8];
#pragma unroll
        for (int i = 0; i < 2; i++)
#pragma unroll
            for (int j = 0; j < 8; j++)
                acc[i][j] = __builtin_amdgcn_mfma_f32_16x16x32_bf16(af[i], bfr[j], acc[i][j], 0, 0, 0);
        asm volatile("s_waitcnt lgkmcnt(0)" ::: "memory");
        __builtin_amdgcn_s_barrier();
        if (ks < 22) {
            // cvt waits a_next (drains tile ks+1's B too -- needed next iter anyway)
            bf16x4 w4;
#pragma unroll
            for (int e = 0; e < 4; e++) w4[e] = (bf16_t)a_next[e];
            *(bf16x4*)&As[buf][arow*32 + acb] = w4;
            BSTAGE(buf, ks + 2);
        }
    }
    // peeled last iteration (ks=23): full drain
    asm volatile("s_waitcnt vmcnt(0)" ::: "memory");
    asm volatile("s_waitcnt lgkmcnt(0)" ::: "memory");
    __builtin_amdgcn_s_barrier();
    {
        bf16x8 af[2], bfr[8];
#pragma unroll
        for (int i = 0; i < 2; i++)
            af[i] = *(const bf16x8*)&As[1][(wr*32 + i*16 + c)*32 + q*8];
#pragma unroll
        for (int j = 0; j < 8; j++)
            bfr[j] = *(const bf16x8*)&Bs[1][(wc*128 + j*16 + c)*32 + q*8];
#pragma unroll
        for (int i = 0; i < 2; i++)
#pragma unroll
            for (int j = 0; j < 8; j++)
                acc[i][j] = __builtin_amdgcn_mfma_f32_16x16x32_bf16(af[i], bfr[j], acc[i][j], 0, 0, 0);
    }

    // epilogue: +bias, LN over this wave's head (128 cols = 8j x 16c),
    // plus per-column partial sums split at the (<=1) batch boundary
    float bias[8], gg[8], bb[8];
#pragma unroll
    for (int j = 0; j < 8; j++) {
        const int d = j*16 + c;
        bias[j] = pb[wc*128 + d];
        gg[j]   = lng[d];
        bb[j]   = lnb[d];
    }
    float cs0[8], cs1[8];
#pragma unroll
    for (int j = 0; j < 8; j++) { cs0[j] = 0.f; cs1[j] = 0.f; }
    const int b0 = m0 / 196;
    const int bL = (m0 + 63) / 196;
#pragma unroll
    for (int i = 0; i < 2; i++) {
#pragma unroll
        for (int r = 0; r < 4; r++) {
            float s = 0.f, s2 = 0.f;
#pragma unroll
            for (int j = 0; j < 8; j++) {
                const float v = acc[i][j][r] + bias[j];
                acc[i][j][r] = v;
                s += v; s2 += v*v;
            }
#pragma unroll
            for (int o = 1; o < 16; o <<= 1) { s += __shfl_xor(s, o); s2 += __shfl_xor(s2, o); }
            const float mu = s * (1.f/128.f);
            const float ms = s2 * (1.f/128.f);
            const float rstd = rsqrtf(ms - mu*mu + LNEPS);
            const int gm = m0 + wr*32 + i*16 + q*4 + r;
            const int bI = gm / 196, l = gm - bI*196;
            bf16_t* dst = hn + (((wc*256 + bI)*196 + l) << 7);
            const bool first = (bI == b0);
#pragma unroll
            for (int j = 0; j < 8; j++) {
                const float v = (acc[i][j][r] - mu)*rstd*gg[j] + bb[j];
                dst[j*16 + c] = (bf16_t)v;
                cs0[j] += first ? v : 0.f;
                cs1[j] += first ? 0.f : v;
            }
        }
    }
    // column-sum reduce: over q (shfl), over row-group waves (LDS), atomicAdd
    __syncthreads();                      // all waves done with As reads
    float* scr = (float*)As;              // 8 waves x 2 buckets x 128 = 8 KB
#pragma unroll
    for (int j = 0; j < 8; j++) {
        float s0 = cs0[j], s1 = cs1[j];
        s0 += __shfl_xor(s0, 16); s0 += __shfl_xor(s0, 32);
        s1 += __shfl_xor(s1, 16); s1 += __shfl_xor(s1, 32);
        if (q == 0) {
            scr[(wv*2 + 0)*128 + j*16 + c] = s0;
            scr[(wv*2 + 1)*128 + j*16 + c] = s1;
        }
    }
    __syncthreads();
    {
        const int hh = (t >> 7) & 3, d = t & 127;   // 4 heads x 128 cols
#pragma unroll
        for (int bucket = 0; bucket < 2; bucket++) {
            if (bucket == 0 || bL > b0) {
                const float s = scr[(hh*2 + bucket)*128 + d]
                              + scr[((hh + 4)*2 + bucket)*128 + d];
                atomicAdd(&csum[((hh*256 + b0 + bucket) << 7) + d], s);
            }
        }
    }
#undef BSTAGE
}

// ---------------------------------------------------------------------------
// K2: per (p,b): raw = x1^T @ x2 (K=196 padded to 224), centering correction,
//     column L2 normalize over d, write cov[b][p][d][e] fp32
// ---------------------------------------------------------------------------
__global__ __launch_bounds__(256, 2)
void k_cov(const bf16_t* __restrict__ hn, const float* __restrict__ colsum,
           float* __restrict__ cov)
{
    __shared__ bf16_t x1s[128*40];
    __shared__ bf16_t x2s[128*40];
    __shared__ float rs1[128], rs2[128];
    __shared__ float colsq[2][128];
    __shared__ float nrm_inv[128];
    __shared__ float mu_s[2];

    const int t = threadIdx.x;
    const int lane = t & 63;
    const int wv = t >> 6;
    const int wr = wv >> 1, wc = wv & 1;
    const int q = lane >> 4;
    const int c = lane & 15;
    const int b = blockIdx.x;
    const int p = blockIdx.y;

    const bf16_t* X1 = hn + (((p*256 + b)*196) << 7);
    const bf16_t* X2 = hn + ((((p+1)*256 + b)*196) << 7);

    if (t < 128) rs1[t] = colsum[((p*256 + b) << 7) + t];
    else         rs2[t & 127] = colsum[(((p+1)*256 + b) << 7) + (t & 127)];
    __syncthreads();
    if (wv == 0) {
        float s = rs1[lane] + rs1[lane + 64];
#pragma unroll
        for (int o = 1; o < 64; o <<= 1) s += __shfl_xor(s, o);
        if (lane == 0) mu_s[0] = s * (1.f/(196.f*128.f));
    } else if (wv == 1) {
        float s = rs2[lane] + rs2[lane + 64];
#pragma unroll
        for (int o = 1; o < 64; o <<= 1) s += __shfl_xor(s, o);
        if (lane == 0) mu_s[1] = s * (1.f/(196.f*128.f));
    }

    floatx4 acc[4][4];
#pragma unroll
    for (int i = 0; i < 4; i++)
#pragma unroll
        for (int j = 0; j < 4; j++)
#pragma unroll
            for (int r = 0; r < 4; r++) acc[i][j][r] = 0.f;

    const int nl = t >> 3;
    const int d0 = (t & 7) * 16;

    for (int n0 = 0; n0 < 224; n0 += 32) {
        __syncthreads();
        const int n = n0 + nl;
        bf16x8 va, vb, wa, wb;
        if (n < 196) {
            const bf16_t* s1 = X1 + (n << 7) + d0;
            const bf16_t* s2 = X2 + (n << 7) + d0;
            va = *(const bf16x8*)s1;
            vb = *(const bf16x8*)(s1 + 8);
            wa = *(const bf16x8*)s2;
            wb = *(const bf16x8*)(s2 + 8);
        } else {
#pragma unroll
            for (int e = 0; e < 8; e++) {
                va[e] = (bf16_t)0.f; vb[e] = (bf16_t)0.f;
                wa[e] = (bf16_t)0.f; wb[e] = (bf16_t)0.f;
            }
        }
#pragma unroll
        for (int e = 0; e < 8; e++) {
            x1s[(d0 + e)*40 + nl]     = va[e];
            x1s[(d0 + 8 + e)*40 + nl] = vb[e];
            x2s[(d0 + e)*40 + nl]     = wa[e];
            x2s[(d0 + 8 + e)*40 + nl] = wb[e];
        }
        __syncthreads();
        bf16x8 af[4], bfr[4];
#pragma unroll
        for (int i = 0; i < 4; i++)
            af[i] = *(const bf16x8*)&x1s[(wr*64 + i*16 + c)*40 + q*8];
#pragma unroll
        for (int j = 0; j < 4; j++)
            bfr[j] = *(const bf16x8*)&x2s[(wc*64 + j*16 + c)*40 + q*8];
#pragma unroll
        for (int i = 0; i < 4; i++)
#pragma unroll
            for (int j = 0; j < 4; j++)
                acc[i][j] = __builtin_amdgcn_mfma_f32_16x16x32_bf16(af[i], bfr[j], acc[i][j], 0, 0, 0);
    }

    const float mu1 = mu_s[0], mu2 = mu_s[1];
    const float invL = 1.f/196.f;
    float csq[4] = {0.f, 0.f, 0.f, 0.f};
#pragma unroll
    for (int i = 0; i < 4; i++)
#pragma unroll
        for (int j = 0; j < 4; j++)
#pragma unroll
            for (int r = 0; r < 4; r++) {
                const int d = wr*64 + i*16 + q*4 + r;
                const int e = wc*64 + j*16 + c;
                const float v = acc[i][j][r]*invL - mu2*rs1[d]*invL - mu1*rs2[e]*invL + mu1*mu2;
                acc[i][j][r] = v;
                csq[j] += v*v;
            }
#pragma unroll
    for (int j = 0; j < 4; j++) {
        float s = csq[j];
        s += __shfl_xor(s, 16);
        s += __shfl_xor(s, 32);
        csq[j] = s;
    }
    if (q == 0) {
#pragma unroll
        for (int j = 0; j < 4; j++) colsq[wr][wc*64 + j*16 + c] = csq[j];
    }
    __syncthreads();
    if (t < 128) {
        const float nr = sqrtf(colsq[0][t] + colsq[1][t]);
        nrm_inv[t] = 1.f / fmaxf(nr, 1e-12f);
    }
    __syncthreads();
    float* dst = cov + ((long)b*3 + p)*16384;
#pragma unroll
    for (int i = 0; i < 4; i++)
#pragma unroll
        for (int j = 0; j < 4; j++) {
            const int e = wc*64 + j*16 + c;
            const float ni = nrm_inv[e];
#pragma unroll
            for (int r = 0; r < 4; r++) {
                const int d = wr*64 + i*16 + q*4 + r;
                dst[(d << 7) + e] = acc[i][j][r] * ni;
            }
        }
}

// ---------------------------------------------------------------------------
// K3: fused conv1+GELU+conv2; 2 blocks per batch (conv2 y-halves) -> 512
// blocks = 2 blocks/CU. Z slice (<=33 rows, 1-row overlap) kept in LDS.
// ---------------------------------------------------------------------------
__global__ __launch_bounds__(256)
void k_convs(const float* __restrict__ cov, const float* __restrict__ w1,
             const float* __restrict__ w2, bf16_t* __restrict__ Xb)
{
    __shared__ float Z[3*33*63];          // 24.9 KB
    __shared__ float W1s[81];
    __shared__ float W2s[81];
    const int t = threadIdx.x;
    const int b = blockIdx.x >> 1, half = blockIdx.x & 1;
    const int zy0 = half ? 32 : 0;        // first global Z row this block needs
    const int nzy = half ? 31 : 33;       // Z rows computed
    const int y20 = half ? 16 : 0;        // first conv2 output row
    const int ny2 = half ? 15 : 16;       // conv2 output rows
    if (t < 81) { W1s[t] = w1[t]; W2s[t] = w2[t]; }
    __syncthreads();
    const float* C = cov + (long)b*3*16384;
    const int ztot = 3*nzy*63;
    for (int idx = t; idx < ztot; idx += 256) {
        const int o = idx / (nzy*63), rem = idx - o*(nzy*63);
        const int yl = rem / 63, xx = rem - yl*63;
        const int y = zy0 + yl;
        float a = 0.f;
#pragma unroll
        for (int i = 0; i < 3; i++) {
            const float* Ci = C + i*16384 + (2*y)*128 + 2*xx;
            const float* Wi = &W1s[o*27 + i*9];
            a += Ci[0]*Wi[0]   + Ci[1]*Wi[1]   + Ci[2]*Wi[2]
               + Ci[128]*Wi[3] + Ci[129]*Wi[4] + Ci[130]*Wi[5]
               + Ci[256]*Wi[6] + Ci[257]*Wi[7] + Ci[258]*Wi[8];
        }
        Z[o*2079 + yl*63 + xx] = 0.5f*a*(1.0f + erff(a*0.70710678118654752f));
    }
    __syncthreads();
    const int c2tot = 3*ny2*31;
    for (int idx = t; idx < c2tot; idx += 256) {
        const int o = idx / (ny2*31), rem = idx - o*(ny2*31);
        const int y2l = rem / 31, x2 = rem - y2l*31;
        float a = 0.f;
#pragma unroll
        for (int i = 0; i < 3; i++) {
            const float* Zi = Z + i*2079 + (2*y2l)*63 + 2*x2;
            const float* Wi = &W2s[(o*3+i)*9];
            a += Zi[0]*Wi[0]   + Zi[1]*Wi[1]   + Zi[2]*Wi[2]
               + Zi[63]*Wi[3]  + Zi[64]*Wi[4]  + Zi[65]*Wi[5]
               + Zi[126]*Wi[6] + Zi[127]*Wi[7] + Zi[128]*Wi[8];
        }
        const int oy2 = y20 + y2l;
        Xb[(long)b*3712 + 768 + o*961 + oy2*31 + x2] = (bf16_t)a;
    }
}

// ---------------------------------------------------------------------------
// K4a: cls fp32 -> bf16 into Xb[b][0..767]; zero K-pad; zero csum slice
// ---------------------------------------------------------------------------
__global__ __launch_bounds__(256)
void k_cvt_cls(const float* __restrict__ cls, bf16_t* __restrict__ Xb,
               float* __restrict__ csum)
{
    const int t = threadIdx.x, b = blockIdx.x;
    for (int k = t; k < 768; k += 256)
        Xb[b*3712 + k] = (bf16_t)cls[b*768 + k];
    if (t < 61) Xb[b*3712 + 3651 + t] = (bf16_t)0.f;
    float* cz = csum + b*512;             // 256 blocks x 512 = 131072 floats
    cz[t] = 0.f; cz[t + 256] = 0.f;
}

// ---------------------------------------------------------------------------
// K4b: build Wb[n][k] bf16, n<1024 (1000 pad), k<3712 (3651 pad)
// ---------------------------------------------------------------------------
__global__ __launch_bounds__(256)
void k_cvt_w(const float* __restrict__ W1, const float* __restrict__ W2,
             bf16_t* __restrict__ Wb)
{
    __shared__ bf16_t tile[32][33];
    const int k0 = blockIdx.x * 32;       // 116 tiles
    const int n0 = blockIdx.y * 32;       // 32 tiles
    const int tx = threadIdx.x & 31, ty = threadIdx.x >> 5;
    for (int i = ty; i < 32; i += 8) {
        const int k = k0 + i, n = n0 + tx;
        float v = 0.f;
        if (n < 1000 && k < 3651)
            v = (k < 768) ? W1[k*1000 + n] : W2[(k-768)*1000 + n];
        tile[i][tx] = (bf16_t)v;
    }
    __syncthreads();
    for (int i = ty; i < 32; i += 8)
        Wb[(n0 + i)*3712 + k0 + tx] = tile[tx][i];
}

// ---------------------------------------------------------------------------
// K4c: MFMA GEMM partial[s][m][n] = Xb[m][ks..] @ Wb[n][ks..]^T
// grid (nt=8, mt=2, split=4); 128x128 tile, K-split 928 each
// ---------------------------------------------------------------------------
__global__ __launch_bounds__(256, 2)
void k_gemm_cls(const bf16_t* __restrict__ Xb, const bf16_t* __restrict__ Wb,
                float* __restrict__ partial)
{
    __shared__ bf16_t As[128*32];
    __shared__ bf16_t Bs[128*32];

    const int t = threadIdx.x;
    const int lane = t & 63;
    const int wv = t >> 6;
    const int wr = wv >> 1, wc = wv & 1;
    const int q = lane >> 4;
    const int c = lane & 15;
    const int nt = blockIdx.x;
    const int mt = blockIdx.y;
    const int sp = blockIdx.z;

    const int srow  = t >> 2;
    const int skoff = (t & 3) * 8;
    const int m0 = mt * 128, n0 = nt * 128;
    const int kbase = sp * 928;
    const bf16_t* ag0 = Xb + (m0 + srow) * 3712 + kbase + skoff;
    const bf16_t* ag1 = Xb + (m0 + srow + 64) * 3712 + kbase + skoff;
    const bf16_t* bg0 = Wb + (n0 + srow) * 3712 + kbase + skoff;
    const bf16_t* bg1 = Wb + (n0 + srow + 64) * 3712 + kbase + skoff;

    floatx4 acc[4][4];
#pragma unroll
    for (int i = 0; i < 4; i++)
#pragma unroll
        for (int j = 0; j < 4; j++)
#pragma unroll
            for (int r = 0; r < 4; r++) acc[i][j][r] = 0.f;

    for (int k0 = 0; k0 < 928; k0 += 32) {
        __syncthreads();
        async_copy16(ag0 + k0, &As[t*8]);
        async_copy16(ag1 + k0, &As[2048 + t*8]);
        async_copy16(bg0 + k0, &Bs[t*8]);
        async_copy16(bg1 + k0, &Bs[2048 + t*8]);
        __syncthreads();
        bf16x8 af[4], bfr[4];
#pragma unroll
        for (int i = 0; i < 4; i++)
            af[i] = *(const bf16x8*)&As[(wr*64 + i*16 + c)*32 + q*8];
#pragma unroll
        for (int j = 0; j < 4; j++)
            bfr[j] = *(const bf16x8*)&Bs[(wc*64 + j*16 + c)*32 + q*8];
#pragma unroll
        for (int i = 0; i < 4; i++)
#pragma unroll
            for (int j = 0; j < 4; j++)
                acc[i][j] = __builtin_amdgcn_mfma_f32_16x16x32_bf16(af[i], bfr[j], acc[i][j], 0, 0, 0);
    }

    float* base = partial + ((long)sp*256 + m0)*1024 + n0;
#pragma unroll
    for (int i = 0; i < 4; i++)
#pragma unroll
        for (int r = 0; r < 4; r++) {
            const int row = wr*64 + i*16 + q*4 + r;
#pragma unroll
            for (int j = 0; j < 4; j++)
                base[row*1024 + wc*64 + j*16 + c] = acc[i][j][r];
        }
}

// ---------------------------------------------------------------------------
// K4d: out[m][n] = 0.5*(sum_s partial[s][m][n] + b1[n] + b2[n]), n<1000
// ---------------------------------------------------------------------------
__global__ __launch_bounds__(256)
void k_cls_fin(const float* __restrict__ partial, const float* __restrict__ b1,
               const float* __restrict__ b2, float* __restrict__ out)
{
    const int idx = blockIdx.x * 256 + threadIdx.x;   // 256,000
    const int m = idx / 1000, n = idx - m*1000;
    float s = partial[(m)*1024 + n] + partial[(256 + m)*1024 + n]
            + partial[(512 + m)*1024 + n] + partial[(768 + m)*1024 + n];
    out[idx] = 0.5f*(s + b1[n] + b2[n]);
}

// ---------------------------------------------------------------------------
extern "C" void kernel_launch(void* const* d_in, const int* in_sizes, int n_in,
                              void* d_out, int out_size, void* d_ws, size_t ws_size,
                              hipStream_t stream) {
    const float* cls = (const float*)d_in[0];
    const float* x   = (const float*)d_in[1];
    const float* pw  = (const float*)d_in[2];
    const float* pb  = (const float*)d_in[3];
    const float* lng = (const float*)d_in[4];
    const float* lnb = (const float*)d_in[5];
    const float* c1w = (const float*)d_in[6];
    const float* c2w = (const float*)d_in[7];
    const float* w1  = (const float*)d_in[8];
    const float* b1  = (const float*)d_in[9];
    const float* w2  = (const float*)d_in[10];
    const float* b2  = (const float*)d_in[11];

    char* ws = (char*)d_ws;
    // lifetimes:
    //   hn      [0, 51,380,224)                 proj_ln out -> cov in
    //   covb    [51,380,224, +50,331,648)       cov out -> convs in
    //   wt      [128,450,560, +786,432)         dead after proj_ln
    //   csum    [129,236,992, +524,288)
    //   Xb      [129,761,280, +1,900,544)
    //   Wb      [131,661,824, +7,602,176)
    //   part    [139,264,000, +4,194,304)
    bf16_t* hn    = (bf16_t*)(ws);
    float*  covb  = (float*) (ws + 51380224ull);
    bf16_t* wt    = (bf16_t*)(ws + 128450560ull);
    float*  csum  = (float*) (ws + 129236992ull);
    bf16_t* Xb    = (bf16_t*)(ws + 129761280ull);
    bf16_t* Wb    = (bf16_t*)(ws + 131661824ull);
    float*  part  = (float*) (ws + 139264000ull);
    float*  out   = (float*)d_out;

    k_transpose_w<<<dim3(16, 24), 256, 0, stream>>>(pw, wt);
    k_cvt_cls<<<256, 256, 0, stream>>>(cls, Xb, csum);
    k_cvt_w<<<dim3(116, 32), 256, 0, stream>>>(w1, w2, Wb);
    k_proj_ln<<<784, 512, 0, stream>>>(x, wt, pb, lng, lnb, hn, csum);
    k_cov<<<dim3(256, 3), 256, 0, stream>>>(hn, csum, covb);
    k_convs<<<512, 256, 0, stream>>>(covb, c1w, c2w, Xb);
    k_gemm_cls<<<dim3(8, 2, 4), 256, 0, stream>>>(Xb, Wb, part);
    k_cls_fin<<<1000, 256, 0, stream>>>(part, b1, b2, out);
}

// Round 4
// 431.416 us; speedup vs baseline: 1.0562x; 1.0367x over previous
//
#include <hip/hip_runtime.h>
#include <hip/hip_bf16.h>
#include <cstdint>

typedef __bf16 bf16_t;
typedef __bf16 bf16x4 __attribute__((ext_vector_type(4)));
typedef __bf16 bf16x8 __attribute__((ext_vector_type(8)));
typedef float floatx4 __attribute__((ext_vector_type(4)));

#define LNEPS 1e-5f

__device__ inline void async_copy16(const bf16_t* g, bf16_t* l) {
    __builtin_amdgcn_global_load_lds((const __attribute__((address_space(1))) void*)g,
                                     (__attribute__((address_space(3))) void*)l,
                                     16, 0, 0);
}

// ---------------------------------------------------------------------------
// K-1: convert x[:,1:,:] fp32 -> bf16 [50176][768] (16B stores).
// Buys L3-residency of A (77 MB bf16) + halves proj_ln staging bytes; the
// fp32-direct variants (rounds 2/3) lose more to the unpipelineable
// reg-staging chain than this 37 us round-trip costs.
// ---------------------------------------------------------------------------
__global__ __launch_bounds__(256)
void k_cvt_x(const float* __restrict__ x, bf16_t* __restrict__ xbf) {
    const int vid = blockIdx.x * 256 + threadIdx.x;   // 8-float chunk, 4,816,896 total
    const int row = vid / 96;                         // 0..50175
    const int kv  = vid - row * 96;
    const int b = row / 196, l = row - (row / 196) * 196;
    const float* src = x + ((b * 197 + l + 1) * 96 + kv) * 8;
    const floatx4 f0 = *(const floatx4*)src;
    const floatx4 f1 = *(const floatx4*)(src + 4);
    bf16x8 o;
#pragma unroll
    for (int e = 0; e < 4; e++) { o[e] = (bf16_t)f0[e]; o[e+4] = (bf16_t)f1[e]; }
    *(bf16x8*)(xbf + vid * 8) = o;
}

// ---------------------------------------------------------------------------
// K0: transpose proj_w (768x512 fp32) -> Wt (512x768 bf16), K-contig B operand
// ---------------------------------------------------------------------------
__global__ __launch_bounds__(256)
void k_transpose_w(const float* __restrict__ w, bf16_t* __restrict__ wt) {
    __shared__ bf16_t tile[32][33];
    const int bx = blockIdx.x;            // n-tile (16)
    const int by = blockIdx.y;            // k-tile (24)
    const int tx = threadIdx.x & 31, ty = threadIdx.x >> 5;  // 32x8
    for (int i = ty; i < 32; i += 8)
        tile[i][tx] = (bf16_t)w[(by*32 + i)*512 + bx*32 + tx];
    __syncthreads();
    for (int i = ty; i < 32; i += 8)
        wt[(bx*32 + i)*768 + by*32 + tx] = tile[tx][i];
}

// ---------------------------------------------------------------------------
// K1: xp = xbf @ Wt^T + b, fused per-head LayerNorm + column sums.
// Round-1 proven loop: 128x128 tile (1 head per block), ALL staging via
// global_load_lds (nothing for the compiler to mis-order), double-buffered,
// stage-next issued BEFORE compute, ONE __syncthreads per K-step, 3 blk/CU.
// Epilogue: shuffle-only LN (wave owns full head) + per-column partial sums
// -> atomicAdd into csum (separate colsum kernel eliminated).
// ---------------------------------------------------------------------------
__global__ __launch_bounds__(256, 3)
void k_proj_ln(const bf16_t* __restrict__ xbf, const bf16_t* __restrict__ wt,
               const float* __restrict__ pb, const float* __restrict__ lng,
               const float* __restrict__ lnb, bf16_t* __restrict__ hn,
               float* __restrict__ csum)
{
    __shared__ bf16_t As[2][128*32];
    __shared__ bf16_t Bs[2][128*32];

    const int t = threadIdx.x;
    const int lane = t & 63;
    const int wv = t >> 6;                // wave 0..3 -> rows wv*32..wv*32+31
    const int q = lane >> 4;
    const int c = lane & 15;
    const int h  = blockIdx.x;            // head 0..3
    const int m0 = blockIdx.y * 128;

    const int srow  = t >> 2;
    const int skoff = (t & 3) * 8;
    const bf16_t* ag = xbf + (m0 + srow) * 768 + skoff;
    const bf16_t* bg = wt + (h*128 + srow) * 768 + skoff;

    floatx4 acc[2][8];
#pragma unroll
    for (int i = 0; i < 2; i++)
#pragma unroll
        for (int j = 0; j < 8; j++)
#pragma unroll
            for (int r = 0; r < 4; r++) acc[i][j][r] = 0.f;

    // prologue: stage k=0 into buf 0
    async_copy16(ag,           &As[0][t*8]);
    async_copy16(ag + 64*768,  &As[0][2048 + t*8]);
    async_copy16(bg,           &Bs[0][t*8]);
    async_copy16(bg + 64*768,  &Bs[0][2048 + t*8]);
    __syncthreads();

    int buf = 0;
    for (int ks = 0; ks < 24; ks++) {
        const int nbuf = buf ^ 1;
        if (ks < 23) {
            const int kn = (ks + 1) * 32;
            async_copy16(ag + kn,          &As[nbuf][t*8]);
            async_copy16(ag + 64*768 + kn, &As[nbuf][2048 + t*8]);
            async_copy16(bg + kn,          &Bs[nbuf][t*8]);
            async_copy16(bg + 64*768 + kn, &Bs[nbuf][2048 + t*8]);
        }
        bf16x8 af[2], bfr[8];
#pragma unroll
        for (int i = 0; i < 2; i++)
            af[i] = *(const bf16x8*)&As[buf][(wv*32 + i*16 + c)*32 + q*8];
#pragma unroll
        for (int j = 0; j < 8; j++)
            bfr[j] = *(const bf16x8*)&Bs[buf][(j*16 + c)*32 + q*8];
#pragma unroll
        for (int i = 0; i < 2; i++)
#pragma unroll
            for (int j = 0; j < 8; j++)
                acc[i][j] = __builtin_amdgcn_mfma_f32_16x16x32_bf16(af[i], bfr[j], acc[i][j], 0, 0, 0);
        __syncthreads();          // drains nbuf staging + buf reads
        buf = nbuf;
    }

    // epilogue: +bias, LN over this wave's head (128 cols = 8j x 16c),
    // plus per-column partial sums split at the (<=1) batch boundary
    float bias[8], gg[8], bb[8];
#pragma unroll
    for (int j = 0; j < 8; j++) {
        const int d = j*16 + c;
        bias[j] = pb[h*128 + d];
        gg[j]   = lng[d];
        bb[j]   = lnb[d];
    }
    float cs0[8], cs1[8];
#pragma unroll
    for (int j = 0; j < 8; j++) { cs0[j] = 0.f; cs1[j] = 0.f; }
    const int b0 = m0 / 196;
    const int bL = (m0 + 127) / 196;
#pragma unroll
    for (int i = 0; i < 2; i++) {
#pragma unroll
        for (int r = 0; r < 4; r++) {
            float s = 0.f, s2 = 0.f;
#pragma unroll
            for (int j = 0; j < 8; j++) {
                const float v = acc[i][j][r] + bias[j];
                acc[i][j][r] = v;
                s += v; s2 += v*v;
            }
#pragma unroll
            for (int o = 1; o < 16; o <<= 1) { s += __shfl_xor(s, o); s2 += __shfl_xor(s2, o); }
            const float mu = s * (1.f/128.f);
            const float ms = s2 * (1.f/128.f);
            const float rstd = rsqrtf(ms - mu*mu + LNEPS);
            const int gm = m0 + wv*32 + i*16 + q*4 + r;
            const int bI = gm / 196, l = gm - bI*196;
            bf16_t* dst = hn + (((h*256 + bI)*196 + l) << 7);
            const bool first = (bI == b0);
#pragma unroll
            for (int j = 0; j < 8; j++) {
                const float v = (acc[i][j][r] - mu)*rstd*gg[j] + bb[j];
                dst[j*16 + c] = (bf16_t)v;
                cs0[j] += first ? v : 0.f;
                cs1[j] += first ? 0.f : v;
            }
        }
    }
    // column-sum reduce: over q (shfl), over waves (LDS), one atomic/col
    float* scr = (float*)As;              // 4 waves x 2 buckets x 128 = 4 KB
#pragma unroll
    for (int j = 0; j < 8; j++) {
        float s0 = cs0[j], s1 = cs1[j];
        s0 += __shfl_xor(s0, 16); s0 += __shfl_xor(s0, 32);
        s1 += __shfl_xor(s1, 16); s1 += __shfl_xor(s1, 32);
        if (q == 0) {
            scr[(wv*2 + 0)*128 + j*16 + c] = s0;
            scr[(wv*2 + 1)*128 + j*16 + c] = s1;
        }
    }
    __syncthreads();
    {
        const int bucket = t >> 7, d = t & 127;
        if (bucket == 0 || bL > b0) {
            const float s = scr[(0*2 + bucket)*128 + d] + scr[(1*2 + bucket)*128 + d]
                          + scr[(2*2 + bucket)*128 + d] + scr[(3*2 + bucket)*128 + d];
            atomicAdd(&csum[((h*256 + b0 + bucket) << 7) + d], s);
        }
    }
}

// ---------------------------------------------------------------------------
// K2: per (p,b): raw = x1^T @ x2 (K=196 padded to 224), centering correction,
//     column L2 normalize over d, write cov[b][p][d][e] fp32
// ---------------------------------------------------------------------------
__global__ __launch_bounds__(256, 2)
void k_cov(const bf16_t* __restrict__ hn, const float* __restrict__ colsum,
           float* __restrict__ cov)
{
    __shared__ bf16_t x1s[128*40];
    __shared__ bf16_t x2s[128*40];
    __shared__ float rs1[128], rs2[128];
    __shared__ float colsq[2][128];
    __shared__ float nrm_inv[128];
    __shared__ float mu_s[2];

    const int t = threadIdx.x;
    const int lane = t & 63;
    const int wv = t >> 6;
    const int wr = wv >> 1, wc = wv & 1;
    const int q = lane >> 4;
    const int c = lane & 15;
    const int b = blockIdx.x;
    const int p = blockIdx.y;

    const bf16_t* X1 = hn + (((p*256 + b)*196) << 7);
    const bf16_t* X2 = hn + ((((p+1)*256 + b)*196) << 7);

    if (t < 128) rs1[t] = colsum[((p*256 + b) << 7) + t];
    else         rs2[t & 127] = colsum[(((p+1)*256 + b) << 7) + (t & 127)];
    __syncthreads();
    if (wv == 0) {
        float s = rs1[lane] + rs1[lane + 64];
#pragma unroll
        for (int o = 1; o < 64; o <<= 1) s += __shfl_xor(s, o);
        if (lane == 0) mu_s[0] = s * (1.f/(196.f*128.f));
    } else if (wv == 1) {
        float s = rs2[lane] + rs2[lane + 64];
#pragma unroll
        for (int o = 1; o < 64; o <<= 1) s += __shfl_xor(s, o);
        if (lane == 0) mu_s[1] = s * (1.f/(196.f*128.f));
    }

    floatx4 acc[4][4];
#pragma unroll
    for (int i = 0; i < 4; i++)
#pragma unroll
        for (int j = 0; j < 4; j++)
#pragma unroll
            for (int r = 0; r < 4; r++) acc[i][j][r] = 0.f;

    const int nl = t >> 3;
    const int d0 = (t & 7) * 16;

    for (int n0 = 0; n0 < 224; n0 += 32) {
        __syncthreads();
        const int n = n0 + nl;
        bf16x8 va, vb, wa, wb;
        if (n < 196) {
            const bf16_t* s1 = X1 + (n << 7) + d0;
            const bf16_t* s2 = X2 + (n << 7) + d0;
            va = *(const bf16x8*)s1;
            vb = *(const bf16x8*)(s1 + 8);
            wa = *(const bf16x8*)s2;
            wb = *(const bf16x8*)(s2 + 8);
        } else {
#pragma unroll
            for (int e = 0; e < 8; e++) {
                va[e] = (bf16_t)0.f; vb[e] = (bf16_t)0.f;
                wa[e] = (bf16_t)0.f; wb[e] = (bf16_t)0.f;
            }
        }
#pragma unroll
        for (int e = 0; e < 8; e++) {
            x1s[(d0 + e)*40 + nl]     = va[e];
            x1s[(d0 + 8 + e)*40 + nl] = vb[e];
            x2s[(d0 + e)*40 + nl]     = wa[e];
            x2s[(d0 + 8 + e)*40 + nl] = wb[e];
        }
        __syncthreads();
        bf16x8 af[4], bfr[4];
#pragma unroll
        for (int i = 0; i < 4; i++)
            af[i] = *(const bf16x8*)&x1s[(wr*64 + i*16 + c)*40 + q*8];
#pragma unroll
        for (int j = 0; j < 4; j++)
            bfr[j] = *(const bf16x8*)&x2s[(wc*64 + j*16 + c)*40 + q*8];
#pragma unroll
        for (int i = 0; i < 4; i++)
#pragma unroll
            for (int j = 0; j < 4; j++)
                acc[i][j] = __builtin_amdgcn_mfma_f32_16x16x32_bf16(af[i], bfr[j], acc[i][j], 0, 0, 0);
    }

    const float mu1 = mu_s[0], mu2 = mu_s[1];
    const float invL = 1.f/196.f;
    float csq[4] = {0.f, 0.f, 0.f, 0.f};
#pragma unroll
    for (int i = 0; i < 4; i++)
#pragma unroll
        for (int j = 0; j < 4; j++)
#pragma unroll
            for (int r = 0; r < 4; r++) {
                const int d = wr*64 + i*16 + q*4 + r;
                const int e = wc*64 + j*16 + c;
                const float v = acc[i][j][r]*invL - mu2*rs1[d]*invL - mu1*rs2[e]*invL + mu1*mu2;
                acc[i][j][r] = v;
                csq[j] += v*v;
            }
#pragma unroll
    for (int j = 0; j < 4; j++) {
        float s = csq[j];
        s += __shfl_xor(s, 16);
        s += __shfl_xor(s, 32);
        csq[j] = s;
    }
    if (q == 0) {
#pragma unroll
        for (int j = 0; j < 4; j++) colsq[wr][wc*64 + j*16 + c] = csq[j];
    }
    __syncthreads();
    if (t < 128) {
        const float nr = sqrtf(colsq[0][t] + colsq[1][t]);
        nrm_inv[t] = 1.f / fmaxf(nr, 1e-12f);
    }
    __syncthreads();
    float* dst = cov + ((long)b*3 + p)*16384;
#pragma unroll
    for (int i = 0; i < 4; i++)
#pragma unroll
        for (int j = 0; j < 4; j++) {
            const int e = wc*64 + j*16 + c;
            const float ni = nrm_inv[e];
#pragma unroll
            for (int r = 0; r < 4; r++) {
                const int d = wr*64 + i*16 + q*4 + r;
                dst[(d << 7) + e] = acc[i][j][r] * ni;
            }
        }
}

// ---------------------------------------------------------------------------
// K3: fused conv1+GELU+conv2; 2 blocks per batch (conv2 y-halves) -> 512
// blocks = 2 blocks/CU. Z slice (<=33 rows, 1-row overlap) kept in LDS.
// ---------------------------------------------------------------------------
__global__ __launch_bounds__(256)
void k_convs(const float* __restrict__ cov, const float* __restrict__ w1,
             const float* __restrict__ w2, bf16_t* __restrict__ Xb)
{
    __shared__ float Z[3*33*63];          // 24.9 KB
    __shared__ float W1s[81];
    __shared__ float W2s[81];
    const int t = threadIdx.x;
    const int b = blockIdx.x >> 1, half = blockIdx.x & 1;
    const int zy0 = half ? 32 : 0;        // first global Z row this block needs
    const int nzy = half ? 31 : 33;       // Z rows computed
    const int y20 = half ? 16 : 0;        // first conv2 output row
    const int ny2 = half ? 15 : 16;       // conv2 output rows
    if (t < 81) { W1s[t] = w1[t]; W2s[t] = w2[t]; }
    __syncthreads();
    const float* C = cov + (long)b*3*16384;
    const int ztot = 3*nzy*63;
    for (int idx = t; idx < ztot; idx += 256) {
        const int o = idx / (nzy*63), rem = idx - o*(nzy*63);
        const int yl = rem / 63, xx = rem - yl*63;
        const int y = zy0 + yl;
        float a = 0.f;
#pragma unroll
        for (int i = 0; i < 3; i++) {
            const float* Ci = C + i*16384 + (2*y)*128 + 2*xx;
            const float* Wi = &W1s[o*27 + i*9];
            a += Ci[0]*Wi[0]   + Ci[1]*Wi[1]   + Ci[2]*Wi[2]
               + Ci[128]*Wi[3] + Ci[129]*Wi[4] + Ci[130]*Wi[5]
               + Ci[256]*Wi[6] + Ci[257]*Wi[7] + Ci[258]*Wi[8];
        }
        Z[o*2079 + yl*63 + xx] = 0.5f*a*(1.0f + erff(a*0.70710678118654752f));
    }
    __syncthreads();
    const int c2tot = 3*ny2*31;
    for (int idx = t; idx < c2tot; idx += 256) {
        const int o = idx / (ny2*31), rem = idx - o*(ny2*31);
        const int y2l = rem / 31, x2 = rem - y2l*31;
        float a = 0.f;
#pragma unroll
        for (int i = 0; i < 3; i++) {
            const float* Zi = Z + i*2079 + (2*y2l)*63 + 2*x2;
            const float* Wi = &W2s[(o*3+i)*9];
            a += Zi[0]*Wi[0]   + Zi[1]*Wi[1]   + Zi[2]*Wi[2]
               + Zi[63]*Wi[3]  + Zi[64]*Wi[4]  + Zi[65]*Wi[5]
               + Zi[126]*Wi[6] + Zi[127]*Wi[7] + Zi[128]*Wi[8];
        }
        const int oy2 = y20 + y2l;
        Xb[(long)b*3712 + 768 + o*961 + oy2*31 + x2] = (bf16_t)a;
    }
}

// ---------------------------------------------------------------------------
// K4a: cls fp32 -> bf16 into Xb[b][0..767]; zero K-pad; zero csum slice
// ---------------------------------------------------------------------------
__global__ __launch_bounds__(256)
void k_cvt_cls(const float* __restrict__ cls, bf16_t* __restrict__ Xb,
               float* __restrict__ csum)
{
    const int t = threadIdx.x, b = blockIdx.x;
    for (int k = t; k < 768; k += 256)
        Xb[b*3712 + k] = (bf16_t)cls[b*768 + k];
    if (t < 61) Xb[b*3712 + 3651 + t] = (bf16_t)0.f;
    float* cz = csum + b*512;             // 256 blocks x 512 = 131072 floats
    cz[t] = 0.f; cz[t + 256] = 0.f;
}

// ---------------------------------------------------------------------------
// K4b: build Wb[n][k] bf16, n<1024 (1000 pad), k<3712 (3651 pad)
// ---------------------------------------------------------------------------
__global__ __launch_bounds__(256)
void k_cvt_w(const float* __restrict__ W1, const float* __restrict__ W2,
             bf16_t* __restrict__ Wb)
{
    __shared__ bf16_t tile[32][33];
    const int k0 = blockIdx.x * 32;       // 116 tiles
    const int n0 = blockIdx.y * 32;       // 32 tiles
    const int tx = threadIdx.x & 31, ty = threadIdx.x >> 5;
    for (int i = ty; i < 32; i += 8) {
        const int k = k0 + i, n = n0 + tx;
        float v = 0.f;
        if (n < 1000 && k < 3651)
            v = (k < 768) ? W1[k*1000 + n] : W2[(k-768)*1000 + n];
        tile[i][tx] = (bf16_t)v;
    }
    __syncthreads();
    for (int i = ty; i < 32; i += 8)
        Wb[(n0 + i)*3712 + k0 + tx] = tile[tx][i];
}

// ---------------------------------------------------------------------------
// K4c: MFMA GEMM partial[s][m][n] = Xb[m][ks..] @ Wb[n][ks..]^T
// grid (nt=8, mt=2, split=4); 128x128 tile, K-split 928 each
// ---------------------------------------------------------------------------
__global__ __launch_bounds__(256, 2)
void k_gemm_cls(const bf16_t* __restrict__ Xb, const bf16_t* __restrict__ Wb,
                float* __restrict__ partial)
{
    __shared__ bf16_t As[128*32];
    __shared__ bf16_t Bs[128*32];

    const int t = threadIdx.x;
    const int lane = t & 63;
    const int wv = t >> 6;
    const int wr = wv >> 1, wc = wv & 1;
    const int q = lane >> 4;
    const int c = lane & 15;
    const int nt = blockIdx.x;
    const int mt = blockIdx.y;
    const int sp = blockIdx.z;

    const int srow  = t >> 2;
    const int skoff = (t & 3) * 8;
    const int m0 = mt * 128, n0 = nt * 128;
    const int kbase = sp * 928;
    const bf16_t* ag0 = Xb + (m0 + srow) * 3712 + kbase + skoff;
    const bf16_t* ag1 = Xb + (m0 + srow + 64) * 3712 + kbase + skoff;
    const bf16_t* bg0 = Wb + (n0 + srow) * 3712 + kbase + skoff;
    const bf16_t* bg1 = Wb + (n0 + srow + 64) * 3712 + kbase + skoff;

    floatx4 acc[4][4];
#pragma unroll
    for (int i = 0; i < 4; i++)
#pragma unroll
        for (int j = 0; j < 4; j++)
#pragma unroll
            for (int r = 0; r < 4; r++) acc[i][j][r] = 0.f;

    for (int k0 = 0; k0 < 928; k0 += 32) {
        __syncthreads();
        async_copy16(ag0 + k0, &As[t*8]);
        async_copy16(ag1 + k0, &As[2048 + t*8]);
        async_copy16(bg0 + k0, &Bs[t*8]);
        async_copy16(bg1 + k0, &Bs[2048 + t*8]);
        __syncthreads();
        bf16x8 af[4], bfr[4];
#pragma unroll
        for (int i = 0; i < 4; i++)
            af[i] = *(const bf16x8*)&As[(wr*64 + i*16 + c)*32 + q*8];
#pragma unroll
        for (int j = 0; j < 4; j++)
            bfr[j] = *(const bf16x8*)&Bs[(wc*64 + j*16 + c)*32 + q*8];
#pragma unroll
        for (int i = 0; i < 4; i++)
#pragma unroll
            for (int j = 0; j < 4; j++)
                acc[i][j] = __builtin_amdgcn_mfma_f32_16x16x32_bf16(af[i], bfr[j], acc[i][j], 0, 0, 0);
    }

    float* base = partial + ((long)sp*256 + m0)*1024 + n0;
#pragma unroll
    for (int i = 0; i < 4; i++)
#pragma unroll
        for (int r = 0; r < 4; r++) {
            const int row = wr*64 + i*16 + q*4 + r;
#pragma unroll
            for (int j = 0; j < 4; j++)
                base[row*1024 + wc*64 + j*16 + c] = acc[i][j][r];
        }
}

// ---------------------------------------------------------------------------
// K4d: out[m][n] = 0.5*(sum_s partial[s][m][n] + b1[n] + b2[n]), n<1000
// ---------------------------------------------------------------------------
__global__ __launch_bounds__(256)
void k_cls_fin(const float* __restrict__ partial, const float* __restrict__ b1,
               const float* __restrict__ b2, float* __restrict__ out)
{
    const int idx = blockIdx.x * 256 + threadIdx.x;   // 256,000
    const int m = idx / 1000, n = idx - m*1000;
    float s = partial[(m)*1024 + n] + partial[(256 + m)*1024 + n]
            + partial[(512 + m)*1024 + n] + partial[(768 + m)*1024 + n];
    out[idx] = 0.5f*(s + b1[n] + b2[n]);
}

// ---------------------------------------------------------------------------
extern "C" void kernel_launch(void* const* d_in, const int* in_sizes, int n_in,
                              void* d_out, int out_size, void* d_ws, size_t ws_size,
                              hipStream_t stream) {
    const float* cls = (const float*)d_in[0];
    const float* x   = (const float*)d_in[1];
    const float* pw  = (const float*)d_in[2];
    const float* pb  = (const float*)d_in[3];
    const float* lng = (const float*)d_in[4];
    const float* lnb = (const float*)d_in[5];
    const float* c1w = (const float*)d_in[6];
    const float* c2w = (const float*)d_in[7];
    const float* w1  = (const float*)d_in[8];
    const float* b1  = (const float*)d_in[9];
    const float* w2  = (const float*)d_in[10];
    const float* b2  = (const float*)d_in[11];

    char* ws = (char*)d_ws;
    // lifetimes:
    //   hn      [0, 51,380,224)                 proj_ln out -> cov in
    //   xbf     [51,380,224, +77,070,336)       dead after proj_ln
    //   covb    [51,380,224, +50,331,648)       reuses xbf; cov out -> convs in
    //   wt      [128,450,560, +786,432)         dead after proj_ln
    //   csum    [129,236,992, +524,288)
    //   Xb      [129,761,280, +1,900,544)
    //   Wb      [131,661,824, +7,602,176)
    //   part    [139,264,000, +4,194,304)
    bf16_t* hn    = (bf16_t*)(ws);
    bf16_t* xbf   = (bf16_t*)(ws + 51380224ull);
    float*  covb  = (float*) (ws + 51380224ull);
    bf16_t* wt    = (bf16_t*)(ws + 128450560ull);
    float*  csum  = (float*) (ws + 129236992ull);
    bf16_t* Xb    = (bf16_t*)(ws + 129761280ull);
    bf16_t* Wb    = (bf16_t*)(ws + 131661824ull);
    float*  part  = (float*) (ws + 139264000ull);
    float*  out   = (float*)d_out;

    k_transpose_w<<<dim3(16, 24), 256, 0, stream>>>(pw, wt);
    k_cvt_x<<<18816, 256, 0, stream>>>(x, xbf);
    k_cvt_cls<<<256, 256, 0, stream>>>(cls, Xb, csum);
    k_cvt_w<<<dim3(116, 32), 256, 0, stream>>>(w1, w2, Wb);
    k_proj_ln<<<dim3(4, 392), 256, 0, stream>>>(xbf, wt, pb, lng, lnb, hn, csum);
    k_cov<<<dim3(256, 3), 256, 0, stream>>>(hn, csum, covb);
    k_convs<<<512, 256, 0, stream>>>(covb, c1w, c2w, Xb);
    k_gemm_cls<<<dim3(8, 2, 4), 256, 0, stream>>>(Xb, Wb, part);
    k_cls_fin<<<1000, 256, 0, stream>>>(part, b1, b2, out);
}

// Round 5
// 422.375 us; speedup vs baseline: 1.0788x; 1.0214x over previous
//
#include <hip/hip_runtime.h>
#include <hip/hip_bf16.h>
#include <cstdint>

typedef __bf16 bf16_t;
typedef __bf16 bf16x4 __attribute__((ext_vector_type(4)));
typedef __bf16 bf16x8 __attribute__((ext_vector_type(8)));
typedef float floatx4 __attribute__((ext_vector_type(4)));

#define LNEPS 1e-5f

__device__ inline void async_copy16(const bf16_t* g, bf16_t* l) {
    __builtin_amdgcn_global_load_lds((const __attribute__((address_space(1))) void*)g,
                                     (__attribute__((address_space(3))) void*)l,
                                     16, 0, 0);
}

// ---------------------------------------------------------------------------
// K-1: convert x[:,1:,:] fp32 -> bf16 [50176][768] (16B stores).
// ---------------------------------------------------------------------------
__global__ __launch_bounds__(256)
void k_cvt_x(const float* __restrict__ x, bf16_t* __restrict__ xbf) {
    const int vid = blockIdx.x * 256 + threadIdx.x;   // 8-float chunk, 4,816,896 total
    const int row = vid / 96;                         // 0..50175
    const int kv  = vid - row * 96;
    const int b = row / 196, l = row - (row / 196) * 196;
    const float* src = x + ((b * 197 + l + 1) * 96 + kv) * 8;
    const floatx4 f0 = *(const floatx4*)src;
    const floatx4 f1 = *(const floatx4*)(src + 4);
    bf16x8 o;
#pragma unroll
    for (int e = 0; e < 4; e++) { o[e] = (bf16_t)f0[e]; o[e+4] = (bf16_t)f1[e]; }
    *(bf16x8*)(xbf + vid * 8) = o;
}

// ---------------------------------------------------------------------------
// K0: transpose proj_w (768x512 fp32) -> Wt (512x768 bf16), K-contig B operand
// ---------------------------------------------------------------------------
__global__ __launch_bounds__(256)
void k_transpose_w(const float* __restrict__ w, bf16_t* __restrict__ wt) {
    __shared__ bf16_t tile[32][33];
    const int bx = blockIdx.x;            // n-tile (16)
    const int by = blockIdx.y;            // k-tile (24)
    const int tx = threadIdx.x & 31, ty = threadIdx.x >> 5;  // 32x8
    for (int i = ty; i < 32; i += 8)
        tile[i][tx] = (bf16_t)w[(by*32 + i)*512 + bx*32 + tx];
    __syncthreads();
    for (int i = ty; i < 32; i += 8)
        wt[(bx*32 + i)*768 + by*32 + tx] = tile[tx][i];
}

// ---------------------------------------------------------------------------
// K1: xp = xbf @ Wt^T + b, fused per-head LayerNorm + column sums.
// 128x128 tile (1 head per block). TRIPLE-buffered LDS, counted-vmcnt raw
// barriers (T3/T4): prologue stages 3 tiles; each step waits vmcnt(8) (tile
// ks landed, tiles ks+1/ks+2 in flight), computes, barriers, stages ks+3.
// Staging is PURE global_load_lds -> no register consumer for the compiler
// to pin a vmcnt(0) on (the rounds-2/3 failure). Peeled tail vmcnt(4)/(0).
// XCD-bijective swizzle: 4 head-blocks of one m-tile -> same XCD L2.
// Epilogue: shuffle-only LN + fused column sums -> atomicAdd csum.
// ---------------------------------------------------------------------------
__global__ __launch_bounds__(256, 3)
void k_proj_ln(const bf16_t* __restrict__ xbf, const bf16_t* __restrict__ wt,
               const float* __restrict__ pb, const float* __restrict__ lng,
               const float* __restrict__ lnb, bf16_t* __restrict__ hn,
               float* __restrict__ csum)
{
    __shared__ bf16_t As[3][128*32];      // 24 KB
    __shared__ bf16_t Bs[3][128*32];      // 24 KB

    const int t = threadIdx.x;
    const int lane = t & 63;
    const int wv = t >> 6;                // wave 0..3 -> rows wv*32..wv*32+31
    const int q = lane >> 4;
    const int c = lane & 15;
    // XCD-bijective: L = xcd + 8*(h + 4*j); m = xcd + 8*j  (392 = 8*49)
    const int L = blockIdx.x;
    const int xcd = L & 7, slot = L >> 3;
    const int h = slot & 3;
    const int m0 = (xcd + 8 * (slot >> 2)) * 128;

    const int srow  = t >> 2;
    const int skoff = (t & 3) * 8;
    const bf16_t* ag = xbf + (m0 + srow) * 768 + skoff;
    const bf16_t* bg = wt + (h*128 + srow) * 768 + skoff;

#define STAGE(B, kk)                                                     \
    {                                                                    \
        const int kn_ = (kk) * 32;                                       \
        async_copy16(ag + kn_,          &As[B][t*8]);                    \
        async_copy16(ag + 64*768 + kn_, &As[B][2048 + t*8]);             \
        async_copy16(bg + kn_,          &Bs[B][t*8]);                    \
        async_copy16(bg + 64*768 + kn_, &Bs[B][2048 + t*8]);             \
    }

#define COMPUTE(B)                                                       \
    {                                                                    \
        bf16x8 af[2], bfr[8];                                            \
        _Pragma("unroll")                                                \
        for (int i = 0; i < 2; i++)                                      \
            af[i] = *(const bf16x8*)&As[B][(wv*32 + i*16 + c)*32 + q*8]; \
        _Pragma("unroll")                                                \
        for (int j = 0; j < 8; j++)                                      \
            bfr[j] = *(const bf16x8*)&Bs[B][(j*16 + c)*32 + q*8];        \
        _Pragma("unroll")                                                \
        for (int i = 0; i < 2; i++)                                      \
            _Pragma("unroll")                                            \
            for (int j = 0; j < 8; j++)                                  \
                acc[i][j] = __builtin_amdgcn_mfma_f32_16x16x32_bf16(af[i], bfr[j], acc[i][j], 0, 0, 0); \
    }

    floatx4 acc[2][8];
#pragma unroll
    for (int i = 0; i < 2; i++)
#pragma unroll
        for (int j = 0; j < 8; j++)
#pragma unroll
            for (int r = 0; r < 4; r++) acc[i][j][r] = 0.f;

    // prologue: stage tiles 0,1,2 (12 gloads/thread in flight)
    STAGE(0, 0);
    STAGE(1, 1);
    STAGE(2, 2);

    for (int ks = 0; ks < 22; ks++) {
        const int buf = ks % 3;
        // tile ks complete (own 4 oldest); tiles ks+1,ks+2 (8) stay in flight
        asm volatile("s_waitcnt vmcnt(8)" ::: "memory");
        __builtin_amdgcn_s_barrier();     // all waves' quarter-tiles published
        COMPUTE(buf);
        __builtin_amdgcn_s_barrier();     // all waves done reading buf
        if (ks < 21) STAGE(buf, ks + 3);
    }
    // peeled tail: ks=22 (outstanding 8 -> wait to 4), ks=23 (drain)
    asm volatile("s_waitcnt vmcnt(4)" ::: "memory");
    __builtin_amdgcn_s_barrier();
    COMPUTE(1);
    __builtin_amdgcn_s_barrier();
    asm volatile("s_waitcnt vmcnt(0)" ::: "memory");
    __builtin_amdgcn_s_barrier();
    COMPUTE(2);

#undef STAGE
#undef COMPUTE

    // epilogue: +bias, LN over this wave's head (128 cols = 8j x 16c),
    // plus per-column partial sums split at the (<=1) batch boundary
    float bias[8], gg[8], bb[8];
#pragma unroll
    for (int j = 0; j < 8; j++) {
        const int d = j*16 + c;
        bias[j] = pb[h*128 + d];
        gg[j]   = lng[d];
        bb[j]   = lnb[d];
    }
    float cs0[8], cs1[8];
#pragma unroll
    for (int j = 0; j < 8; j++) { cs0[j] = 0.f; cs1[j] = 0.f; }
    const int b0 = m0 / 196;
    const int bL = (m0 + 127) / 196;
#pragma unroll
    for (int i = 0; i < 2; i++) {
#pragma unroll
        for (int r = 0; r < 4; r++) {
            float s = 0.f, s2 = 0.f;
#pragma unroll
            for (int j = 0; j < 8; j++) {
                const float v = acc[i][j][r] + bias[j];
                acc[i][j][r] = v;
                s += v; s2 += v*v;
            }
#pragma unroll
            for (int o = 1; o < 16; o <<= 1) { s += __shfl_xor(s, o); s2 += __shfl_xor(s2, o); }
            const float mu = s * (1.f/128.f);
            const float ms = s2 * (1.f/128.f);
            const float rstd = rsqrtf(ms - mu*mu + LNEPS);
            const int gm = m0 + wv*32 + i*16 + q*4 + r;
            const int bI = gm / 196, l = gm - bI*196;
            bf16_t* dst = hn + (((h*256 + bI)*196 + l) << 7);
            const bool first = (bI == b0);
#pragma unroll
            for (int j = 0; j < 8; j++) {
                const float v = (acc[i][j][r] - mu)*rstd*gg[j] + bb[j];
                dst[j*16 + c] = (bf16_t)v;
                cs0[j] += first ? v : 0.f;
                cs1[j] += first ? 0.f : v;
            }
        }
    }
    // column-sum reduce: over q (shfl), over waves (LDS scratch in As[0]),
    // one atomic per (bucket,col). Last COMPUTE read As[2]/Bs[2]; scratch
    // uses As[0] bytes 0..4095 -> no overlap with pending reads.
    float* scr = (float*)As;
#pragma unroll
    for (int j = 0; j < 8; j++) {
        float s0 = cs0[j], s1 = cs1[j];
        s0 += __shfl_xor(s0, 16); s0 += __shfl_xor(s0, 32);
        s1 += __shfl_xor(s1, 16); s1 += __shfl_xor(s1, 32);
        if (q == 0) {
            scr[(wv*2 + 0)*128 + j*16 + c] = s0;
            scr[(wv*2 + 1)*128 + j*16 + c] = s1;
        }
    }
    __syncthreads();
    {
        const int bucket = t >> 7, d = t & 127;
        if (bucket == 0 || bL > b0) {
            const float s = scr[(0*2 + bucket)*128 + d] + scr[(1*2 + bucket)*128 + d]
                          + scr[(2*2 + bucket)*128 + d] + scr[(3*2 + bucket)*128 + d];
            atomicAdd(&csum[((h*256 + b0 + bucket) << 7) + d], s);
        }
    }
}

// ---------------------------------------------------------------------------
// K2: per (p,b): raw = x1^T @ x2 (K=196 padded to 224), centering correction,
//     column L2 normalize over d, write cov[b][p][d][e] fp32
// ---------------------------------------------------------------------------
__global__ __launch_bounds__(256, 2)
void k_cov(const bf16_t* __restrict__ hn, const float* __restrict__ colsum,
           float* __restrict__ cov)
{
    __shared__ bf16_t x1s[128*40];
    __shared__ bf16_t x2s[128*40];
    __shared__ float rs1[128], rs2[128];
    __shared__ float colsq[2][128];
    __shared__ float nrm_inv[128];
    __shared__ float mu_s[2];

    const int t = threadIdx.x;
    const int lane = t & 63;
    const int wv = t >> 6;
    const int wr = wv >> 1, wc = wv & 1;
    const int q = lane >> 4;
    const int c = lane & 15;
    const int b = blockIdx.x;
    const int p = blockIdx.y;

    const bf16_t* X1 = hn + (((p*256 + b)*196) << 7);
    const bf16_t* X2 = hn + ((((p+1)*256 + b)*196) << 7);

    if (t < 128) rs1[t] = colsum[((p*256 + b) << 7) + t];
    else         rs2[t & 127] = colsum[(((p+1)*256 + b) << 7) + (t & 127)];
    __syncthreads();
    if (wv == 0) {
        float s = rs1[lane] + rs1[lane + 64];
#pragma unroll
        for (int o = 1; o < 64; o <<= 1) s += __shfl_xor(s, o);
        if (lane == 0) mu_s[0] = s * (1.f/(196.f*128.f));
    } else if (wv == 1) {
        float s = rs2[lane] + rs2[lane + 64];
#pragma unroll
        for (int o = 1; o < 64; o <<= 1) s += __shfl_xor(s, o);
        if (lane == 0) mu_s[1] = s * (1.f/(196.f*128.f));
    }

    floatx4 acc[4][4];
#pragma unroll
    for (int i = 0; i < 4; i++)
#pragma unroll
        for (int j = 0; j < 4; j++)
#pragma unroll
            for (int r = 0; r < 4; r++) acc[i][j][r] = 0.f;

    const int nl = t >> 3;
    const int d0 = (t & 7) * 16;

    for (int n0 = 0; n0 < 224; n0 += 32) {
        __syncthreads();
        const int n = n0 + nl;
        bf16x8 va, vb, wa, wb;
        if (n < 196) {
            const bf16_t* s1 = X1 + (n << 7) + d0;
            const bf16_t* s2 = X2 + (n << 7) + d0;
            va = *(const bf16x8*)s1;
            vb = *(const bf16x8*)(s1 + 8);
            wa = *(const bf16x8*)s2;
            wb = *(const bf16x8*)(s2 + 8);
        } else {
#pragma unroll
            for (int e = 0; e < 8; e++) {
                va[e] = (bf16_t)0.f; vb[e] = (bf16_t)0.f;
                wa[e] = (bf16_t)0.f; wb[e] = (bf16_t)0.f;
            }
        }
#pragma unroll
        for (int e = 0; e < 8; e++) {
            x1s[(d0 + e)*40 + nl]     = va[e];
            x1s[(d0 + 8 + e)*40 + nl] = vb[e];
            x2s[(d0 + e)*40 + nl]     = wa[e];
            x2s[(d0 + 8 + e)*40 + nl] = wb[e];
        }
        __syncthreads();
        bf16x8 af[4], bfr[4];
#pragma unroll
        for (int i = 0; i < 4; i++)
            af[i] = *(const bf16x8*)&x1s[(wr*64 + i*16 + c)*40 + q*8];
#pragma unroll
        for (int j = 0; j < 4; j++)
            bfr[j] = *(const bf16x8*)&x2s[(wc*64 + j*16 + c)*40 + q*8];
#pragma unroll
        for (int i = 0; i < 4; i++)
#pragma unroll
            for (int j = 0; j < 4; j++)
                acc[i][j] = __builtin_amdgcn_mfma_f32_16x16x32_bf16(af[i], bfr[j], acc[i][j], 0, 0, 0);
    }

    const float mu1 = mu_s[0], mu2 = mu_s[1];
    const float invL = 1.f/196.f;
    float csq[4] = {0.f, 0.f, 0.f, 0.f};
#pragma unroll
    for (int i = 0; i < 4; i++)
#pragma unroll
        for (int j = 0; j < 4; j++)
#pragma unroll
            for (int r = 0; r < 4; r++) {
                const int d = wr*64 + i*16 + q*4 + r;
                const int e = wc*64 + j*16 + c;
                const float v = acc[i][j][r]*invL - mu2*rs1[d]*invL - mu1*rs2[e]*invL + mu1*mu2;
                acc[i][j][r] = v;
                csq[j] += v*v;
            }
#pragma unroll
    for (int j = 0; j < 4; j++) {
        float s = csq[j];
        s += __shfl_xor(s, 16);
        s += __shfl_xor(s, 32);
        csq[j] = s;
    }
    if (q == 0) {
#pragma unroll
        for (int j = 0; j < 4; j++) colsq[wr][wc*64 + j*16 + c] = csq[j];
    }
    __syncthreads();
    if (t < 128) {
        const float nr = sqrtf(colsq[0][t] + colsq[1][t]);
        nrm_inv[t] = 1.f / fmaxf(nr, 1e-12f);
    }
    __syncthreads();
    float* dst = cov + ((long)b*3 + p)*16384;
#pragma unroll
    for (int i = 0; i < 4; i++)
#pragma unroll
        for (int j = 0; j < 4; j++) {
            const int e = wc*64 + j*16 + c;
            const float ni = nrm_inv[e];
#pragma unroll
            for (int r = 0; r < 4; r++) {
                const int d = wr*64 + i*16 + q*4 + r;
                dst[(d << 7) + e] = acc[i][j][r] * ni;
            }
        }
}

// ---------------------------------------------------------------------------
// K3: fused conv1+GELU+conv2; 2 blocks per batch (conv2 y-halves) -> 512
// blocks = 2 blocks/CU. Z slice (<=33 rows, 1-row overlap) kept in LDS.
// ---------------------------------------------------------------------------
__global__ __launch_bounds__(256)
void k_convs(const float* __restrict__ cov, const float* __restrict__ w1,
             const float* __restrict__ w2, bf16_t* __restrict__ Xb)
{
    __shared__ float Z[3*33*63];          // 24.9 KB
    __shared__ float W1s[81];
    __shared__ float W2s[81];
    const int t = threadIdx.x;
    const int b = blockIdx.x >> 1, half = blockIdx.x & 1;
    const int zy0 = half ? 32 : 0;        // first global Z row this block needs
    const int nzy = half ? 31 : 33;       // Z rows computed
    const int y20 = half ? 16 : 0;        // first conv2 output row
    const int ny2 = half ? 15 : 16;       // conv2 output rows
    if (t < 81) { W1s[t] = w1[t]; W2s[t] = w2[t]; }
    __syncthreads();
    const float* C = cov + (long)b*3*16384;
    const int ztot = 3*nzy*63;
    for (int idx = t; idx < ztot; idx += 256) {
        const int o = idx / (nzy*63), rem = idx - o*(nzy*63);
        const int yl = rem / 63, xx = rem - yl*63;
        const int y = zy0 + yl;
        float a = 0.f;
#pragma unroll
        for (int i = 0; i < 3; i++) {
            const float* Ci = C + i*16384 + (2*y)*128 + 2*xx;
            const float* Wi = &W1s[o*27 + i*9];
            a += Ci[0]*Wi[0]   + Ci[1]*Wi[1]   + Ci[2]*Wi[2]
               + Ci[128]*Wi[3] + Ci[129]*Wi[4] + Ci[130]*Wi[5]
               + Ci[256]*Wi[6] + Ci[257]*Wi[7] + Ci[258]*Wi[8];
        }
        Z[o*2079 + yl*63 + xx] = 0.5f*a*(1.0f + erff(a*0.70710678118654752f));
    }
    __syncthreads();
    const int c2tot = 3*ny2*31;
    for (int idx = t; idx < c2tot; idx += 256) {
        const int o = idx / (ny2*31), rem = idx - o*(ny2*31);
        const int y2l = rem / 31, x2 = rem - y2l*31;
        float a = 0.f;
#pragma unroll
        for (int i = 0; i < 3; i++) {
            const float* Zi = Z + i*2079 + (2*y2l)*63 + 2*x2;
            const float* Wi = &W2s[(o*3+i)*9];
            a += Zi[0]*Wi[0]   + Zi[1]*Wi[1]   + Zi[2]*Wi[2]
               + Zi[63]*Wi[3]  + Zi[64]*Wi[4]  + Zi[65]*Wi[5]
               + Zi[126]*Wi[6] + Zi[127]*Wi[7] + Zi[128]*Wi[8];
        }
        const int oy2 = y20 + y2l;
        Xb[(long)b*3712 + 768 + o*961 + oy2*31 + x2] = (bf16_t)a;
    }
}

// ---------------------------------------------------------------------------
// K4a: cls fp32 -> bf16 into Xb[b][0..767]; zero K-pad; zero csum slice
// ---------------------------------------------------------------------------
__global__ __launch_bounds__(256)
void k_cvt_cls(const float* __restrict__ cls, bf16_t* __restrict__ Xb,
               float* __restrict__ csum)
{
    const int t = threadIdx.x, b = blockIdx.x;
    for (int k = t; k < 768; k += 256)
        Xb[b*3712 + k] = (bf16_t)cls[b*768 + k];
    if (t < 61) Xb[b*3712 + 3651 + t] = (bf16_t)0.f;
    float* cz = csum + b*512;             // 256 blocks x 512 = 131072 floats
    cz[t] = 0.f; cz[t + 256] = 0.f;
}

// ---------------------------------------------------------------------------
// K4b: build Wb[n][k] bf16, n<1024 (1000 pad), k<3712 (3651 pad)
// ---------------------------------------------------------------------------
__global__ __launch_bounds__(256)
void k_cvt_w(const float* __restrict__ W1, const float* __restrict__ W2,
             bf16_t* __restrict__ Wb)
{
    __shared__ bf16_t tile[32][33];
    const int k0 = blockIdx.x * 32;       // 116 tiles
    const int n0 = blockIdx.y * 32;       // 32 tiles
    const int tx = threadIdx.x & 31, ty = threadIdx.x >> 5;
    for (int i = ty; i < 32; i += 8) {
        const int k = k0 + i, n = n0 + tx;
        float v = 0.f;
        if (n < 1000 && k < 3651)
            v = (k < 768) ? W1[k*1000 + n] : W2[(k-768)*1000 + n];
        tile[i][tx] = (bf16_t)v;
    }
    __syncthreads();
    for (int i = ty; i < 32; i += 8)
        Wb[(n0 + i)*3712 + k0 + tx] = tile[tx][i];
}

// ---------------------------------------------------------------------------
// K4c: MFMA GEMM partial[s][m][n] = Xb[m][ks..] @ Wb[n][ks..]^T
// grid (nt=8, mt=2, split=4); 128x128 tile, K-split 928 each
// ---------------------------------------------------------------------------
__global__ __launch_bounds__(256, 2)
void k_gemm_cls(const bf16_t* __restrict__ Xb, const bf16_t* __restrict__ Wb,
                float* __restrict__ partial)
{
    __shared__ bf16_t As[128*32];
    __shared__ bf16_t Bs[128*32];

    const int t = threadIdx.x;
    const int lane = t & 63;
    const int wv = t >> 6;
    const int wr = wv >> 1, wc = wv & 1;
    const int q = lane >> 4;
    const int c = lane & 15;
    const int nt = blockIdx.x;
    const int mt = blockIdx.y;
    const int sp = blockIdx.z;

    const int srow  = t >> 2;
    const int skoff = (t & 3) * 8;
    const int m0 = mt * 128, n0 = nt * 128;
    const int kbase = sp * 928;
    const bf16_t* ag0 = Xb + (m0 + srow) * 3712 + kbase + skoff;
    const bf16_t* ag1 = Xb + (m0 + srow + 64) * 3712 + kbase + skoff;
    const bf16_t* bg0 = Wb + (n0 + srow) * 3712 + kbase + skoff;
    const bf16_t* bg1 = Wb + (n0 + srow + 64) * 3712 + kbase + skoff;

    floatx4 acc[4][4];
#pragma unroll
    for (int i = 0; i < 4; i++)
#pragma unroll
        for (int j = 0; j < 4; j++)
#pragma unroll
            for (int r = 0; r < 4; r++) acc[i][j][r] = 0.f;

    for (int k0 = 0; k0 < 928; k0 += 32) {
        __syncthreads();
        async_copy16(ag0 + k0, &As[t*8]);
        async_copy16(ag1 + k0, &As[2048 + t*8]);
        async_copy16(bg0 + k0, &Bs[t*8]);
        async_copy16(bg1 + k0, &Bs[2048 + t*8]);
        __syncthreads();
        bf16x8 af[4], bfr[4];
#pragma unroll
        for (int i = 0; i < 4; i++)
            af[i] = *(const bf16x8*)&As[(wr*64 + i*16 + c)*32 + q*8];
#pragma unroll
        for (int j = 0; j < 4; j++)
            bfr[j] = *(const bf16x8*)&Bs[(wc*64 + j*16 + c)*32 + q*8];
#pragma unroll
        for (int i = 0; i < 4; i++)
#pragma unroll
            for (int j = 0; j < 4; j++)
                acc[i][j] = __builtin_amdgcn_mfma_f32_16x16x32_bf16(af[i], bfr[j], acc[i][j], 0, 0, 0);
    }

    float* base = partial + ((long)sp*256 + m0)*1024 + n0;
#pragma unroll
    for (int i = 0; i < 4; i++)
#pragma unroll
        for (int r = 0; r < 4; r++) {
            const int row = wr*64 + i*16 + q*4 + r;
#pragma unroll
            for (int j = 0; j < 4; j++)
                base[row*1024 + wc*64 + j*16 + c] = acc[i][j][r];
        }
}

// ---------------------------------------------------------------------------
// K4d: out[m][n] = 0.5*(sum_s partial[s][m][n] + b1[n] + b2[n]), n<1000
// ---------------------------------------------------------------------------
__global__ __launch_bounds__(256)
void k_cls_fin(const float* __restrict__ partial, const float* __restrict__ b1,
               const float* __restrict__ b2, float* __restrict__ out)
{
    const int idx = blockIdx.x * 256 + threadIdx.x;   // 256,000
    const int m = idx / 1000, n = idx - m*1000;
    float s = partial[(m)*1024 + n] + partial[(256 + m)*1024 + n]
            + partial[(512 + m)*1024 + n] + partial[(768 + m)*1024 + n];
    out[idx] = 0.5f*(s + b1[n] + b2[n]);
}

// ---------------------------------------------------------------------------
extern "C" void kernel_launch(void* const* d_in, const int* in_sizes, int n_in,
                              void* d_out, int out_size, void* d_ws, size_t ws_size,
                              hipStream_t stream) {
    const float* cls = (const float*)d_in[0];
    const float* x   = (const float*)d_in[1];
    const float* pw  = (const float*)d_in[2];
    const float* pb  = (const float*)d_in[3];
    const float* lng = (const float*)d_in[4];
    const float* lnb = (const float*)d_in[5];
    const float* c1w = (const float*)d_in[6];
    const float* c2w = (const float*)d_in[7];
    const float* w1  = (const float*)d_in[8];
    const float* b1  = (const float*)d_in[9];
    const float* w2  = (const float*)d_in[10];
    const float* b2  = (const float*)d_in[11];

    char* ws = (char*)d_ws;
    // lifetimes:
    //   hn      [0, 51,380,224)                 proj_ln out -> cov in
    //   xbf     [51,380,224, +77,070,336)       dead after proj_ln
    //   covb    [51,380,224, +50,331,648)       reuses xbf; cov out -> convs in
    //   wt      [128,450,560, +786,432)         dead after proj_ln
    //   csum    [129,236,992, +524,288)
    //   Xb      [129,761,280, +1,900,544)
    //   Wb      [131,661,824, +7,602,176)
    //   part    [139,264,000, +4,194,304)
    bf16_t* hn    = (bf16_t*)(ws);
    bf16_t* xbf   = (bf16_t*)(ws + 51380224ull);
    float*  covb  = (float*) (ws + 51380224ull);
    bf16_t* wt    = (bf16_t*)(ws + 128450560ull);
    float*  csum  = (float*) (ws + 129236992ull);
    bf16_t* Xb    = (bf16_t*)(ws + 129761280ull);
    bf16_t* Wb    = (bf16_t*)(ws + 131661824ull);
    float*  part  = (float*) (ws + 139264000ull);
    float*  out   = (float*)d_out;

    k_transpose_w<<<dim3(16, 24), 256, 0, stream>>>(pw, wt);
    k_cvt_x<<<18816, 256, 0, stream>>>(x, xbf);
    k_cvt_cls<<<256, 256, 0, stream>>>(cls, Xb, csum);
    k_cvt_w<<<dim3(116, 32), 256, 0, stream>>>(w1, w2, Wb);
    k_proj_ln<<<1568, 256, 0, stream>>>(xbf, wt, pb, lng, lnb, hn, csum);
    k_cov<<<dim3(256, 3), 256, 0, stream>>>(hn, csum, covb);
    k_convs<<<512, 256, 0, stream>>>(covb, c1w, c2w, Xb);
    k_gemm_cls<<<dim3(8, 2, 4), 256, 0, stream>>>(Xb, Wb, part);
    k_cls_fin<<<1000, 256, 0, stream>>>(part, b1, b2, out);
}